// Round 6
// baseline (355.974 us; speedup 1.0000x reference)
//
#include <hip/hip_runtime.h>
#include <hip/hip_bf16.h>
#include <cstdint>
#include <cstddef>

#define D_MODEL 1024
#define SEQ     2048
#define NTOK    4096   // B*S
#define NH      16
#define HD      64

typedef __attribute__((ext_vector_type(8))) short sh8;
typedef __attribute__((ext_vector_type(4))) float f32x4;

#define GLL(g, s) __builtin_amdgcn_global_load_lds(                                   \
    (const __attribute__((address_space(1))) void*)(g),                               \
    (__attribute__((address_space(3))) void*)(s), 16, 0, 0)

__device__ __forceinline__ unsigned short f2b(float f) {
  union { float f; unsigned u; } v; v.f = f;
  unsigned r = v.u + 0x7FFFu + ((v.u >> 16) & 1u);
  return (unsigned short)(r >> 16);
}
__device__ __forceinline__ float b2f(unsigned short h) {
  union { unsigned u; float f; } v; v.u = ((unsigned)h) << 16;
  return v.f;
}

// ---------------- fused fp32 -> bf16 cast for all 6 weights ----------------
__global__ __launch_bounds__(256) void cast6_kernel(
    const float* __restrict__ q, const float* __restrict__ k, const float* __restrict__ v,
    const float* __restrict__ o, const float* __restrict__ u, const float* __restrict__ d,
    unsigned short* __restrict__ oq, unsigned short* __restrict__ ok,
    unsigned short* __restrict__ ov, unsigned short* __restrict__ oo,
    unsigned short* __restrict__ ou, unsigned short* __restrict__ od) {
  int bid = blockIdx.x;
  const float* src; unsigned short* dst; int base;
  if      (bid < 1024) { src = q; dst = oq; base = bid; }
  else if (bid < 2048) { src = k; dst = ok; base = bid - 1024; }
  else if (bid < 3072) { src = v; dst = ov; base = bid - 2048; }
  else if (bid < 4096) { src = o; dst = oo; base = bid - 3072; }
  else if (bid < 8192) { src = u; dst = ou; base = bid - 4096; }
  else                 { src = d; dst = od; base = bid - 8192; }
  int i = base * 1024 + threadIdx.x * 4;
  float4 vv = *(const float4*)(src + i);
  ushort4 w;
  w.x = f2b(vv.x); w.y = f2b(vv.y); w.z = f2b(vv.z); w.w = f2b(vv.w);
  *(ushort4*)(dst + i) = w;
}

// ---------------- LayerNorm (torch var ddof=1), bf16 out ----------------
__global__ __launch_bounds__(256) void ln_kernel(const float* __restrict__ x,
                                                 const float* __restrict__ msc,
                                                 const float* __restrict__ ssc,
                                                 unsigned short* __restrict__ out) {
  const int t = blockIdx.x;
  const int tid = threadIdx.x;
  const float4 v = ((const float4*)(x + (size_t)t * D_MODEL))[tid];
  float s = v.x + v.y + v.z + v.w;
  float q = v.x * v.x + v.y * v.y + v.z * v.z + v.w * v.w;
  #pragma unroll
  for (int off = 32; off; off >>= 1) {
    s += __shfl_xor(s, off);
    q += __shfl_xor(q, off);
  }
  __shared__ float sh[8];
  const int w = tid >> 6;
  if ((tid & 63) == 0) { sh[w * 2] = s; sh[w * 2 + 1] = q; }
  __syncthreads();
  s = sh[0] + sh[2] + sh[4] + sh[6];
  q = sh[1] + sh[3] + sh[5] + sh[7];
  const float mean = s * (1.0f / D_MODEL);
  const float var = (q - (float)D_MODEL * mean * mean) * (1.0f / (D_MODEL - 1));
  const float rstd = rsqrtf(var + 1e-9f);
  const float4 ms = ((const float4*)msc)[tid];
  const float4 ss = ((const float4*)ssc)[tid];
  ushort4 o;
  o.x = f2b((v.x - mean) * rstd * ss.x + ms.x);
  o.y = f2b((v.y - mean) * rstd * ss.y + ms.y);
  o.z = f2b((v.z - mean) * rstd * ss.z + ms.z);
  o.w = f2b((v.w - mean) * rstd * ss.w + ms.w);
  ((ushort4*)(out + (size_t)t * D_MODEL))[tid] = o;
}

// -------- fused: out = x + p0 + p1 ; oln = LN2(out) (one pass per row) --------
__global__ __launch_bounds__(256) void reduce_ln_kernel(
    const unsigned short* __restrict__ p0, const unsigned short* __restrict__ p1,
    const float* __restrict__ x, const float* __restrict__ msc,
    const float* __restrict__ ssc, float* __restrict__ out,
    unsigned short* __restrict__ oln) {
  const int t = blockIdx.x;
  const int tid = threadIdx.x;
  const size_t base = (size_t)t * D_MODEL + tid * 4;
  ushort4 a = *(const ushort4*)(p0 + base);
  ushort4 b = *(const ushort4*)(p1 + base);
  float4 xv = *(const float4*)(x + base);
  float4 r;
  r.x = xv.x + b2f(a.x) + b2f(b.x);
  r.y = xv.y + b2f(a.y) + b2f(b.y);
  r.z = xv.z + b2f(a.z) + b2f(b.z);
  r.w = xv.w + b2f(a.w) + b2f(b.w);
  *(float4*)(out + base) = r;
  float s = r.x + r.y + r.z + r.w;
  float q = r.x * r.x + r.y * r.y + r.z * r.z + r.w * r.w;
  #pragma unroll
  for (int off = 32; off; off >>= 1) {
    s += __shfl_xor(s, off);
    q += __shfl_xor(q, off);
  }
  __shared__ float sh[8];
  const int w = tid >> 6;
  if ((tid & 63) == 0) { sh[w * 2] = s; sh[w * 2 + 1] = q; }
  __syncthreads();
  s = sh[0] + sh[2] + sh[4] + sh[6];
  q = sh[1] + sh[3] + sh[5] + sh[7];
  const float mean = s * (1.0f / D_MODEL);
  const float var = (q - (float)D_MODEL * mean * mean) * (1.0f / (D_MODEL - 1));
  const float rstd = rsqrtf(var + 1e-9f);
  const float4 ms = ((const float4*)msc)[tid];
  const float4 ss = ((const float4*)ssc)[tid];
  ushort4 o;
  o.x = f2b((r.x - mean) * rstd * ss.x + ms.x);
  o.y = f2b((r.y - mean) * rstd * ss.y + ms.y);
  o.z = f2b((r.z - mean) * rstd * ss.z + ms.z);
  o.w = f2b((r.w - mean) * rstd * ss.w + ms.w);
  *(ushort4*)(oln + base) = o;
}

// ---------------- V transpose: qkv[tok][2048+d] -> vt[b][d][s] ----------------
__global__ __launch_bounds__(256) void vtrans_kernel(const unsigned short* __restrict__ qkv,
                                                     unsigned short* __restrict__ vt) {
  __shared__ unsigned short T[64][72];
  const int st = blockIdx.x;            // s-tile 0..31
  const int b  = blockIdx.y >> 4;
  const int dt = blockIdx.y & 15;       // d-tile 0..15
  const int tid = threadIdx.x;
  const int s0 = st * 64, d0 = dt * 64;
  const int r = tid >> 2, c0 = (tid & 3) * 16;
  const unsigned short* src = qkv + ((size_t)b * SEQ + s0 + r) * 3072 + 2 * D_MODEL + d0 + c0;
  *(uint4*)&T[r][c0]     = *(const uint4*)(src);
  *(uint4*)&T[r][c0 + 8] = *(const uint4*)(src + 8);
  __syncthreads();
  unsigned short buf[16] __attribute__((aligned(16)));
  #pragma unroll
  for (int j = 0; j < 16; j++) buf[j] = T[c0 + j][r];
  unsigned short* dst = vt + ((size_t)b * D_MODEL + d0 + r) * SEQ + s0 + c0;
  *(uint4*)(dst)     = *(uint4*)&buf[0];
  *(uint4*)(dst + 8) = *(uint4*)&buf[8];
}

// =====================================================================
// 128x128 NT GEMM: BK=64, 4 waves (2x2), single-buffered 32KB LDS, GLL
// staging, XOR chunk swizzle, bijective XCD rect remap.
// EP: 0 = bf16 store, 1 = exp2-GELU bf16 store,
//     2 = f32 atomic-add into C0 (split-K partials fold into out directly;
//         removes the reduce2 pass.  out = x + attn is already final base
//         because reduce_ln is stream-ordered before this kernel.)
// =====================================================================
template <int EP, int GX, int GY, int GZ, int CHX, int CHY>
__global__ __launch_bounds__(256) void gemm_nt(const unsigned short* __restrict__ A,
                                               const unsigned short* __restrict__ B,
                                               int N, int LD, int Kext,
                                               unsigned short* __restrict__ Cbf,
                                               unsigned short* __restrict__ Cbf2) {
  constexpr int NRX = GX / CHX;
  constexpr int NRY = GY / CHY;
  static_assert(NRX * NRY * GZ == 8, "rect count must equal 8 XCDs");
  __shared__ __align__(16) unsigned short As[128 * 64];
  __shared__ __align__(16) unsigned short Bs[128 * 64];
  const int tid = threadIdx.x;
  const int w = tid >> 6, l = tid & 63, ln = tid & 15, quad = (tid & 63) >> 4;
  const int wr = (w >> 1) * 64, wc = (w & 1) * 64;

  // XCD-locality remap: physical block l%8 -> XCD l%8 owns rect #(l%8)
  const int lb  = blockIdx.x;
  const int xcd = lb & 7, slot = lb >> 3;
  const int rx  = xcd % NRX, rem = xcd / NRX;
  const int ry  = rem % NRY, rz = rem / NRY;
  const int sx  = slot % CHX, sy = slot / CHX;
  const int bx  = rx * CHX + sx;
  const int by  = ry * CHY + sy;
  const int bz  = rz;

  const int m0 = by * 128, n0 = bx * 128;
  const int koff = bz * Kext;

  const int sr = l >> 3, sc = l & 7;
  const unsigned short* AgS = A + (size_t)(m0 + w * 32 + sr) * LD + koff + ((sc ^ sr) * 8);
  const unsigned short* BgS = B + (size_t)(n0 + w * 32 + sr) * LD + koff + ((sc ^ sr) * 8);
  unsigned short* AsW = &As[(w * 32) * 64];
  unsigned short* BsW = &Bs[(w * 32) * 64];

  f32x4 acc[4][4] = {};

  for (int k0 = 0; k0 < Kext; k0 += 64) {
    __syncthreads();
    #pragma unroll
    for (int off = 0; off < 32; off += 8) {
      GLL(AgS + k0 + (size_t)off * LD, AsW + off * 64);
      GLL(BgS + k0 + (size_t)off * LD, BsW + off * 64);
    }
    __syncthreads();
    sh8 af[2][4], bfr[2][4];
    #pragma unroll
    for (int kk = 0; kk < 2; kk++) {
      #pragma unroll
      for (int i = 0; i < 4; i++)
        af[kk][i]  = *(const sh8*)&As[(wr + i * 16 + ln) * 64 + (((kk * 4 + quad) ^ (ln & 7)) * 8)];
      #pragma unroll
      for (int j = 0; j < 4; j++)
        bfr[kk][j] = *(const sh8*)&Bs[(wc + j * 16 + ln) * 64 + (((kk * 4 + quad) ^ (ln & 7)) * 8)];
    }
    #pragma unroll
    for (int kk = 0; kk < 2; kk++)
      #pragma unroll
      for (int i = 0; i < 4; i++)
        #pragma unroll
        for (int j = 0; j < 4; j++)
          acc[i][j] = __builtin_amdgcn_mfma_f32_16x16x32_bf16(af[kk][i], bfr[kk][j], acc[i][j], 0, 0, 0);
  }

  unsigned short* C = (EP == 2) ? Cbf : (bz ? Cbf2 : Cbf);
  #pragma unroll
  for (int i = 0; i < 4; i++) {
    #pragma unroll
    for (int rr = 0; rr < 4; rr++) {
      const int gm = m0 + wr + i * 16 + quad * 4 + rr;
      #pragma unroll
      for (int j = 0; j < 4; j++) {
        const int gn = n0 + wc + j * 16 + ln;
        float v = acc[i][j][rr];
        if (EP == 2) {
          unsafeAtomicAdd((float*)C + (size_t)gm * N + gn, v);
        } else {
          if (EP == 1) {
            // tanh-form GELU via exp2: g = v*e/(e+1), e = 2^(2.30219*(v+0.044715 v^3))
            const float vc = fminf(v, 8.0f);
            const float e = exp2f(2.3021906f * fmaf(0.044715f * vc * vc, vc, vc));
            v = v * e / (e + 1.0f);
          }
          C[(size_t)gm * N + gn] = f2b(v);
        }
      }
    }
  }
}

// ---------------- Flash attention, causal, BM=64, BN=64, fixed-max softmax ----
// R6: split-key removed — one block per (bh, q-tile) walks ALL key tiles,
// computes the full row-sum l locally, applies 1/l in the epilogue and
// writes `pre` directly (no attn_combine pass, no l buffers, half the
// partial-write traffic).  Longest-q-tiles-first + bh-fastest XCD swizzle
// keeps load balance and K/V L2 locality (4 bh/XCD, 2 MB working set).
__global__ __launch_bounds__(256) void attn_kernel(const unsigned short* __restrict__ qkv,
                                                   const unsigned short* __restrict__ vt,
                                                   unsigned short* __restrict__ pre) {
  const int bh = blockIdx.x;                    // XCD swizzle: bh fastest
  const int qt = (SEQ / 64 - 1) - blockIdx.y;   // reversed: long blocks first
  const int b = bh >> 4, h = bh & 15;
  const int tid = threadIdx.x;
  const int w = tid >> 6, l = tid & 63, ln = tid & 15, quad = (tid & 63) >> 4;
  const int q0 = qt * 64;

  __shared__ __align__(16) unsigned short Ks[64 * 64];   // [key][d], chunk ^ (key&7)
  __shared__ __align__(16) unsigned short Vs[64 * 64];   // [d][key], chunk ^ (d&7)
  __shared__ __align__(16) unsigned short Ps[4][16 * 72];

  const size_t rstride = 3 * D_MODEL;
  const unsigned short* Qg = qkv + (size_t)b * SEQ * rstride + h * HD;
  const unsigned short* Kg = Qg + D_MODEL;
  const unsigned short* Vg = vt + ((size_t)b * D_MODEL + h * HD) * SEQ;

  sh8 qf[2];
  {
    const unsigned short* qrow = Qg + (size_t)(q0 + w * 16 + ln) * rstride + quad * 8;
    qf[0] = *(const sh8*)(qrow);
    qf[1] = *(const sh8*)(qrow + 32);
  }

  const int lr3 = l >> 3, lp3 = l & 7;
  const int cS = (lp3 ^ lr3) * 8;
  const unsigned short* KgS = Kg + (size_t)(w * 16 + lr3) * rstride + cS;
  unsigned short* KsW = &Ks[(w * 16) * 64];
  const unsigned short* VgS = Vg + (size_t)(w * 16 + lr3) * SEQ + cS;
  unsigned short* VsW = &Vs[(w * 16) * 64];
  unsigned short* Psw = &Ps[w][0];

  f32x4 o[4] = {};
  float lpart[4] = {0.f, 0.f, 0.f, 0.f};
  const int rbase = q0 + w * 16 + quad * 4;

  auto tile = [&](int kt, bool diag) {
    __syncthreads();
    GLL(KgS + (size_t)(kt * 64) * rstride,     KsW);
    GLL(KgS + (size_t)(kt * 64 + 8) * rstride, KsW + 8 * 64);
    GLL(VgS + kt * 64,           VsW);
    GLL(VgS + 8 * SEQ + kt * 64, VsW + 8 * 64);
    __syncthreads();

    #pragma unroll
    for (int ct = 0; ct < 4; ct++) {
      const int k = ct * 16 + ln;
      f32x4 zz = {};
      zz = __builtin_amdgcn_mfma_f32_16x16x32_bf16(
          qf[0], *(const sh8*)&Ks[k * 64 + ((quad ^ (k & 7)) * 8)], zz, 0, 0, 0);
      zz = __builtin_amdgcn_mfma_f32_16x16x32_bf16(
          qf[1], *(const sh8*)&Ks[k * 64 + (((4 + quad) ^ (k & 7)) * 8)], zz, 0, 0, 0);
      const int cg = kt * 64 + ct * 16 + ln;
      #pragma unroll
      for (int rr = 0; rr < 4; rr++) {
        float e = exp2f(fmaf(zz[rr], 0.18033688011112042f, -5.770780163555853f));
        if (diag && cg > rbase + rr) e = 0.0f;
        lpart[rr] += e;
        Psw[(quad * 4 + rr) * 72 + ct * 16 + ln] = f2b(e);
      }
    }

    #pragma unroll
    for (int kk = 0; kk < 2; kk++) {
      sh8 pf = *(const sh8*)&Psw[ln * 72 + kk * 32 + quad * 8];
      #pragma unroll
      for (int c2 = 0; c2 < 4; c2++) {
        const int d = c2 * 16 + ln;
        sh8 vf = *(const sh8*)&Vs[d * 64 + ((((kk * 4 + quad) ^ (d & 7))) * 8)];
        o[c2] = __builtin_amdgcn_mfma_f32_16x16x32_bf16(pf, vf, o[c2], 0, 0, 0);
      }
    }
  };

  for (int kt = 0; kt < qt; kt++) tile(kt, false);
  tile(qt, true);

  #pragma unroll
  for (int rr = 0; rr < 4; rr++) {
    #pragma unroll
    for (int off = 1; off < 16; off <<= 1) lpart[rr] += __shfl_xor(lpart[rr], off);
  }

  #pragma unroll
  for (int rr = 0; rr < 4; rr++) {
    const float inv = 1.0f / lpart[rr];
    const int row = q0 + w * 16 + quad * 4 + rr;
    const size_t base = ((size_t)b * SEQ + row) * D_MODEL + h * HD;
    #pragma unroll
    for (int c2 = 0; c2 < 4; c2++)
      pre[base + c2 * 16 + ln] = f2b(o[c2][rr] * inv);
  }
}

extern "C" void kernel_launch(void* const* d_in, const int* in_sizes, int n_in,
                              void* d_out, int out_size, void* d_ws, size_t ws_size,
                              hipStream_t stream) {
  const float* x    = (const float*)d_in[0];
  const float* Wq   = (const float*)d_in[1];
  const float* Wk   = (const float*)d_in[2];
  const float* Wv   = (const float*)d_in[3];
  const float* Wo   = (const float*)d_in[4];
  const float* Wup  = (const float*)d_in[5];
  const float* Wdn  = (const float*)d_in[6];
  const float* ln1m = (const float*)d_in[7];
  const float* ln1s = (const float*)d_in[8];
  const float* ln2m = (const float*)d_in[9];
  const float* ln2s = (const float*)d_in[10];
  float* out = (float*)d_out;

  unsigned short* ws = (unsigned short*)d_ws;
  size_t off = 0;
  unsigned short* wqkv = ws + off; off += (size_t)3072 * 1024;
  unsigned short* wo   = ws + off; off += (size_t)1024 * 1024;
  unsigned short* wup  = ws + off; off += (size_t)4096 * 1024;
  unsigned short* wdn  = ws + off; off += (size_t)1024 * 4096;
  unsigned short* xln  = ws + off; off += (size_t)NTOK * 1024;
  unsigned short* qkvb = ws + off; off += (size_t)NTOK * 3072;
  unsigned short* pre  = ws + off; off += (size_t)NTOK * 1024;
  unsigned short* mid  = qkvb;   // up-GEMM out [4096][4096] spans qkvb+pre exactly
  unsigned short* vtg  = xln;    // V^T aliases xln during attention (dead until LN2)
  unsigned short* po0  = qkvb;   // O-proj partials (qkvb dead after attn)
  unsigned short* po1  = qkvb + (size_t)NTOK * 1024;

  // fused weight casts (12288 blocks x 1024 elems)
  cast6_kernel<<<12288, 256, 0, stream>>>(Wq, Wk, Wv, Wo, Wup, Wdn,
      wqkv, wqkv + (size_t)1024 * 1024, wqkv + (size_t)2 * 1024 * 1024, wo, wup, wdn);

  // LN1
  ln_kernel<<<NTOK, 256, 0, stream>>>(x, ln1m, ln1s, xln);
  // fused QKV projection: logical 24x32, XCD rect 12x8 (2x4 rects)
  gemm_nt<0, 24, 32, 1, 12, 8><<<768, 256, 0, stream>>>(xln, wqkv, 3072, 1024, 1024, qkvb, nullptr);
  // V transpose (xln region becomes vtg)
  vtrans_kernel<<<dim3(32, 32), 256, 0, stream>>>(qkvb, vtg);
  // causal flash attention, no split-key, 1/l applied in epilogue -> pre
  attn_kernel<<<dim3(2 * NH, SEQ / 64), 256, 0, stream>>>(qkvb, vtg, pre);
  // O-projection: logical 8x32x2, XCD rect 4x16 (2x2x2 rects), split-K=2
  gemm_nt<0, 8, 32, 2, 4, 16><<<512, 256, 0, stream>>>(pre, wo, 1024, 1024, 512, po0, po1);
  // fused: out = x + po0 + po1 ; xln = LN2(out)
  reduce_ln_kernel<<<NTOK, 256, 0, stream>>>(po0, po1, x, ln2m, ln2s, out, xln);
  // MLP up + exp2-GELU: logical 32x32, XCD rect 8x16 (4x2 rects)
  gemm_nt<1, 32, 32, 1, 8, 16><<<1024, 256, 0, stream>>>(xln, wup, 4096, 1024, 1024, mid, nullptr);
  // MLP down: split-K=2, f32 atomic-add epilogue directly into out (no reduce2)
  gemm_nt<2, 8, 32, 2, 8, 8><<<512, 256, 0, stream>>>(mid, wdn, 1024, 4096, 2048,
                                                      (unsigned short*)out, nullptr);
}

// Round 8
// 353.912 us; speedup vs baseline: 1.0058x; 1.0058x over previous
//
#include <hip/hip_runtime.h>
#include <hip/hip_bf16.h>
#include <cstdint>
#include <cstddef>

#define D_MODEL 1024
#define SEQ     2048
#define NTOK    4096   // B*S
#define NH      16
#define HD      64

typedef __attribute__((ext_vector_type(8))) short sh8;
typedef __attribute__((ext_vector_type(4))) float f32x4;

#define GLL(g, s) __builtin_amdgcn_global_load_lds(                                   \
    (const __attribute__((address_space(1))) void*)(g),                               \
    (__attribute__((address_space(3))) void*)(s), 16, 0, 0)

__device__ __forceinline__ unsigned short f2b(float f) {
  union { float f; unsigned u; } v; v.f = f;
  unsigned r = v.u + 0x7FFFu + ((v.u >> 16) & 1u);
  return (unsigned short)(r >> 16);
}
__device__ __forceinline__ float b2f(unsigned short h) {
  union { unsigned u; float f; } v; v.u = ((unsigned)h) << 16;
  return v.f;
}

// ---------------- fused fp32 -> bf16 cast for all 6 weights ----------------
__global__ __launch_bounds__(256) void cast6_kernel(
    const float* __restrict__ q, const float* __restrict__ k, const float* __restrict__ v,
    const float* __restrict__ o, const float* __restrict__ u, const float* __restrict__ d,
    unsigned short* __restrict__ oq, unsigned short* __restrict__ ok,
    unsigned short* __restrict__ ov, unsigned short* __restrict__ oo,
    unsigned short* __restrict__ ou, unsigned short* __restrict__ od) {
  int bid = blockIdx.x;
  const float* src; unsigned short* dst; int base;
  if      (bid < 1024) { src = q; dst = oq; base = bid; }
  else if (bid < 2048) { src = k; dst = ok; base = bid - 1024; }
  else if (bid < 3072) { src = v; dst = ov; base = bid - 2048; }
  else if (bid < 4096) { src = o; dst = oo; base = bid - 3072; }
  else if (bid < 8192) { src = u; dst = ou; base = bid - 4096; }
  else                 { src = d; dst = od; base = bid - 8192; }
  int i = base * 1024 + threadIdx.x * 4;
  float4 vv = *(const float4*)(src + i);
  ushort4 w;
  w.x = f2b(vv.x); w.y = f2b(vv.y); w.z = f2b(vv.z); w.w = f2b(vv.w);
  *(ushort4*)(dst + i) = w;
}

// ---------------- LayerNorm (torch var ddof=1), bf16 out ----------------
__global__ __launch_bounds__(256) void ln_kernel(const float* __restrict__ x,
                                                 const float* __restrict__ msc,
                                                 const float* __restrict__ ssc,
                                                 unsigned short* __restrict__ out) {
  const int t = blockIdx.x;
  const int tid = threadIdx.x;
  const float4 v = ((const float4*)(x + (size_t)t * D_MODEL))[tid];
  float s = v.x + v.y + v.z + v.w;
  float q = v.x * v.x + v.y * v.y + v.z * v.z + v.w * v.w;
  #pragma unroll
  for (int off = 32; off; off >>= 1) {
    s += __shfl_xor(s, off);
    q += __shfl_xor(q, off);
  }
  __shared__ float sh[8];
  const int w = tid >> 6;
  if ((tid & 63) == 0) { sh[w * 2] = s; sh[w * 2 + 1] = q; }
  __syncthreads();
  s = sh[0] + sh[2] + sh[4] + sh[6];
  q = sh[1] + sh[3] + sh[5] + sh[7];
  const float mean = s * (1.0f / D_MODEL);
  const float var = (q - (float)D_MODEL * mean * mean) * (1.0f / (D_MODEL - 1));
  const float rstd = rsqrtf(var + 1e-9f);
  const float4 ms = ((const float4*)msc)[tid];
  const float4 ss = ((const float4*)ssc)[tid];
  ushort4 o;
  o.x = f2b((v.x - mean) * rstd * ss.x + ms.x);
  o.y = f2b((v.y - mean) * rstd * ss.y + ms.y);
  o.z = f2b((v.z - mean) * rstd * ss.z + ms.z);
  o.w = f2b((v.w - mean) * rstd * ss.w + ms.w);
  ((ushort4*)(out + (size_t)t * D_MODEL))[tid] = o;
}

// -------- fused: out = x + p0 + p1 ; oln = LN2(out) (one pass per row) --------
__global__ __launch_bounds__(256) void reduce_ln_kernel(
    const unsigned short* __restrict__ p0, const unsigned short* __restrict__ p1,
    const float* __restrict__ x, const float* __restrict__ msc,
    const float* __restrict__ ssc, float* __restrict__ out,
    unsigned short* __restrict__ oln) {
  const int t = blockIdx.x;
  const int tid = threadIdx.x;
  const size_t base = (size_t)t * D_MODEL + tid * 4;
  ushort4 a = *(const ushort4*)(p0 + base);
  ushort4 b = *(const ushort4*)(p1 + base);
  float4 xv = *(const float4*)(x + base);
  float4 r;
  r.x = xv.x + b2f(a.x) + b2f(b.x);
  r.y = xv.y + b2f(a.y) + b2f(b.y);
  r.z = xv.z + b2f(a.z) + b2f(b.z);
  r.w = xv.w + b2f(a.w) + b2f(b.w);
  *(float4*)(out + base) = r;
  float s = r.x + r.y + r.z + r.w;
  float q = r.x * r.x + r.y * r.y + r.z * r.z + r.w * r.w;
  #pragma unroll
  for (int off = 32; off; off >>= 1) {
    s += __shfl_xor(s, off);
    q += __shfl_xor(q, off);
  }
  __shared__ float sh[8];
  const int w = tid >> 6;
  if ((tid & 63) == 0) { sh[w * 2] = s; sh[w * 2 + 1] = q; }
  __syncthreads();
  s = sh[0] + sh[2] + sh[4] + sh[6];
  q = sh[1] + sh[3] + sh[5] + sh[7];
  const float mean = s * (1.0f / D_MODEL);
  const float var = (q - (float)D_MODEL * mean * mean) * (1.0f / (D_MODEL - 1));
  const float rstd = rsqrtf(var + 1e-9f);
  const float4 ms = ((const float4*)msc)[tid];
  const float4 ss = ((const float4*)ssc)[tid];
  ushort4 o;
  o.x = f2b((r.x - mean) * rstd * ss.x + ms.x);
  o.y = f2b((r.y - mean) * rstd * ss.y + ms.y);
  o.z = f2b((r.z - mean) * rstd * ss.z + ms.z);
  o.w = f2b((r.w - mean) * rstd * ss.w + ms.w);
  *(ushort4*)(oln + base) = o;
}

// ---------------- split-K partial reduce: out += p0 + p1 ----------------------
__global__ __launch_bounds__(256) void reduce2_kernel(const unsigned short* __restrict__ p0,
                                                      const unsigned short* __restrict__ p1,
                                                      float* __restrict__ out) {
  int i = (blockIdx.x * 256 + threadIdx.x) * 4;
  ushort4 a = *(const ushort4*)(p0 + i);
  ushort4 b = *(const ushort4*)(p1 + i);
  float4 base = *(const float4*)(out + i);
  float4 r;
  r.x = base.x + b2f(a.x) + b2f(b.x);
  r.y = base.y + b2f(a.y) + b2f(b.y);
  r.z = base.z + b2f(a.z) + b2f(b.z);
  r.w = base.w + b2f(a.w) + b2f(b.w);
  *(float4*)(out + i) = r;
}

// ---------------- attention split-key combine: pre = (p0+p1)/(l0+l1) ----------
__global__ __launch_bounds__(256) void attn_combine_kernel(
    unsigned short* __restrict__ p0, const unsigned short* __restrict__ p1,
    const float* __restrict__ l0, const float* __restrict__ l1) {
  int i = (blockIdx.x * 256 + threadIdx.x) * 4;
  const int tok = i >> 10, ch = i & 1023;
  const int b = tok >> 11, s = tok & 2047, h = ch >> 6;
  const int lidx = ((b << 4) + h) * 2048 + s;
  const float inv = 1.0f / (l0[lidx] + l1[lidx]);
  ushort4 a = *(const ushort4*)(p0 + i);
  ushort4 c = *(const ushort4*)(p1 + i);
  ushort4 r;
  r.x = f2b((b2f(a.x) + b2f(c.x)) * inv);
  r.y = f2b((b2f(a.y) + b2f(c.y)) * inv);
  r.z = f2b((b2f(a.z) + b2f(c.z)) * inv);
  r.w = f2b((b2f(a.w) + b2f(c.w)) * inv);
  *(ushort4*)(p0 + i) = r;
}

// ---------------- V transpose: qkv[tok][2048+d] -> vt[b][d][s] ----------------
__global__ __launch_bounds__(256) void vtrans_kernel(const unsigned short* __restrict__ qkv,
                                                     unsigned short* __restrict__ vt) {
  __shared__ unsigned short T[64][72];
  const int st = blockIdx.x;            // s-tile 0..31
  const int b  = blockIdx.y >> 4;
  const int dt = blockIdx.y & 15;       // d-tile 0..15
  const int tid = threadIdx.x;
  const int s0 = st * 64, d0 = dt * 64;
  const int r = tid >> 2, c0 = (tid & 3) * 16;
  const unsigned short* src = qkv + ((size_t)b * SEQ + s0 + r) * 3072 + 2 * D_MODEL + d0 + c0;
  *(uint4*)&T[r][c0]     = *(const uint4*)(src);
  *(uint4*)&T[r][c0 + 8] = *(const uint4*)(src + 8);
  __syncthreads();
  unsigned short buf[16] __attribute__((aligned(16)));
  #pragma unroll
  for (int j = 0; j < 16; j++) buf[j] = T[c0 + j][r];
  unsigned short* dst = vt + ((size_t)b * D_MODEL + d0 + r) * SEQ + s0 + c0;
  *(uint4*)(dst)     = *(uint4*)&buf[0];
  *(uint4*)(dst + 8) = *(uint4*)&buf[8];
}

// =====================================================================
// 128x128 NT GEMM: BK=64, 4 waves (2x2), single-buffered 32KB LDS, GLL
// staging, XOR chunk swizzle, bijective XCD rect remap.
// R7: MFMA operand order SWAPPED (mfma(b,a)) -> each thread's f32x4 holds
// 4 consecutive COLUMNS of one row (row = wr+i*16+ln, col = wc+j*16+
// quad*4+rr).  Same arithmetic; epilogue becomes 16 packed 8-byte stores
// per thread instead of 64 scalar 2-byte stores (the K=1024 shapes spend
// ~8 K-steps' worth of time in the old epilogue -> ~35% overhead).
// EP: 0 = bf16 store, 1 = exp2-GELU bf16 store.  (EP==2 atomic variant
// removed: R6 showed it perturbs sibling instantiations' codegen.)
// =====================================================================
template <int EP, int GX, int GY, int GZ, int CHX, int CHY>
__global__ __launch_bounds__(256) void gemm_nt(const unsigned short* __restrict__ A,
                                               const unsigned short* __restrict__ B,
                                               int N, int LD, int Kext,
                                               unsigned short* __restrict__ Cbf,
                                               unsigned short* __restrict__ Cbf2) {
  constexpr int NRX = GX / CHX;
  constexpr int NRY = GY / CHY;
  static_assert(NRX * NRY * GZ == 8, "rect count must equal 8 XCDs");
  __shared__ __align__(16) unsigned short As[128 * 64];
  __shared__ __align__(16) unsigned short Bs[128 * 64];
  const int tid = threadIdx.x;
  const int w = tid >> 6, l = tid & 63, ln = tid & 15, quad = (tid & 63) >> 4;
  const int wr = (w >> 1) * 64, wc = (w & 1) * 64;

  // XCD-locality remap: physical block l%8 -> XCD l%8 owns rect #(l%8)
  const int lb  = blockIdx.x;
  const int xcd = lb & 7, slot = lb >> 3;
  const int rx  = xcd % NRX, rem = xcd / NRX;
  const int ry  = rem % NRY, rz = rem / NRY;
  const int sx  = slot % CHX, sy = slot / CHX;
  const int bx  = rx * CHX + sx;
  const int by  = ry * CHY + sy;
  const int bz  = rz;

  const int m0 = by * 128, n0 = bx * 128;
  const int koff = bz * Kext;

  const int sr = l >> 3, sc = l & 7;
  const unsigned short* AgS = A + (size_t)(m0 + w * 32 + sr) * LD + koff + ((sc ^ sr) * 8);
  const unsigned short* BgS = B + (size_t)(n0 + w * 32 + sr) * LD + koff + ((sc ^ sr) * 8);
  unsigned short* AsW = &As[(w * 32) * 64];
  unsigned short* BsW = &Bs[(w * 32) * 64];

  f32x4 acc[4][4] = {};

  for (int k0 = 0; k0 < Kext; k0 += 64) {
    __syncthreads();
    #pragma unroll
    for (int off = 0; off < 32; off += 8) {
      GLL(AgS + k0 + (size_t)off * LD, AsW + off * 64);
      GLL(BgS + k0 + (size_t)off * LD, BsW + off * 64);
    }
    __syncthreads();
    sh8 af[2][4], bfr[2][4];
    #pragma unroll
    for (int kk = 0; kk < 2; kk++) {
      #pragma unroll
      for (int i = 0; i < 4; i++)
        af[kk][i]  = *(const sh8*)&As[(wr + i * 16 + ln) * 64 + (((kk * 4 + quad) ^ (ln & 7)) * 8)];
      #pragma unroll
      for (int j = 0; j < 4; j++)
        bfr[kk][j] = *(const sh8*)&Bs[(wc + j * 16 + ln) * 64 + (((kk * 4 + quad) ^ (ln & 7)) * 8)];
    }
    // operand-swapped: acc[i][j] is the transposed fragment (row=ln)
    #pragma unroll
    for (int kk = 0; kk < 2; kk++)
      #pragma unroll
      for (int i = 0; i < 4; i++)
        #pragma unroll
        for (int j = 0; j < 4; j++)
          acc[i][j] = __builtin_amdgcn_mfma_f32_16x16x32_bf16(bfr[kk][j], af[kk][i], acc[i][j], 0, 0, 0);
  }

  unsigned short* C = bz ? Cbf2 : Cbf;
  #pragma unroll
  for (int i = 0; i < 4; i++) {
    const int gm = m0 + wr + i * 16 + ln;
    unsigned short* Crow = C + (size_t)gm * N + n0 + wc + quad * 4;
    #pragma unroll
    for (int j = 0; j < 4; j++) {
      ushort4 pk;
      #pragma unroll
      for (int rr = 0; rr < 4; rr++) {
        float v = acc[i][j][rr];
        if (EP == 1) {
          // tanh-form GELU via exp2: g = v*e/(e+1), e = 2^(2.30219*(v+0.044715 v^3))
          const float vc = fminf(v, 8.0f);
          const float e = exp2f(2.3021906f * fmaf(0.044715f * vc * vc, vc, vc));
          v = v * e / (e + 1.0f);
        }
        ((unsigned short*)&pk)[rr] = f2b(v);
      }
      *(ushort4*)(Crow + j * 16) = pk;
    }
  }
}

// ---------------- Flash attention, causal, BM=64, BN=64, fixed-max softmax ----
__global__ __launch_bounds__(256) void attn_kernel(const unsigned short* __restrict__ qkv,
                                                   const unsigned short* __restrict__ vt,
                                                   unsigned short* __restrict__ p0,
                                                   unsigned short* __restrict__ p1,
                                                   float* __restrict__ l0,
                                                   float* __restrict__ l1) {
  const int bh = blockIdx.x;                    // XCD swizzle: bh fastest
  const int qt = (SEQ / 64 - 1) - blockIdx.y;   // reversed: long blocks first
  const int z  = blockIdx.z;
  const int b = bh >> 4, h = bh & 15;
  const int tid = threadIdx.x;
  const int w = tid >> 6, l = tid & 63, ln = tid & 15, quad = (tid & 63) >> 4;
  const int q0 = qt * 64;

  __shared__ __align__(16) unsigned short Ks[64 * 64];   // [key][d], chunk ^ (key&7)
  __shared__ __align__(16) unsigned short Vs[64 * 64];   // [d][key], chunk ^ (d&7)
  __shared__ __align__(16) unsigned short Ps[4][16 * 72];

  const size_t rstride = 3 * D_MODEL;
  const unsigned short* Qg = qkv + (size_t)b * SEQ * rstride + h * HD;
  const unsigned short* Kg = Qg + D_MODEL;
  const unsigned short* Vg = vt + ((size_t)b * D_MODEL + h * HD) * SEQ;

  sh8 qf[2];
  {
    const unsigned short* qrow = Qg + (size_t)(q0 + w * 16 + ln) * rstride + quad * 8;
    qf[0] = *(const sh8*)(qrow);
    qf[1] = *(const sh8*)(qrow + 32);
  }

  const int lr3 = l >> 3, lp3 = l & 7;
  const int cS = (lp3 ^ lr3) * 8;
  const unsigned short* KgS = Kg + (size_t)(w * 16 + lr3) * rstride + cS;
  unsigned short* KsW = &Ks[(w * 16) * 64];
  const unsigned short* VgS = Vg + (size_t)(w * 16 + lr3) * SEQ + cS;
  unsigned short* VsW = &Vs[(w * 16) * 64];
  unsigned short* Psw = &Ps[w][0];

  f32x4 o[4] = {};
  float lpart[4] = {0.f, 0.f, 0.f, 0.f};
  const int rbase = q0 + w * 16 + quad * 4;

  auto tile = [&](int kt, bool diag) {
    __syncthreads();
    GLL(KgS + (size_t)(kt * 64) * rstride,     KsW);
    GLL(KgS + (size_t)(kt * 64 + 8) * rstride, KsW + 8 * 64);
    GLL(VgS + kt * 64,           VsW);
    GLL(VgS + 8 * SEQ + kt * 64, VsW + 8 * 64);
    __syncthreads();

    #pragma unroll
    for (int ct = 0; ct < 4; ct++) {
      const int k = ct * 16 + ln;
      f32x4 zz = {};
      zz = __builtin_amdgcn_mfma_f32_16x16x32_bf16(
          qf[0], *(const sh8*)&Ks[k * 64 + ((quad ^ (k & 7)) * 8)], zz, 0, 0, 0);
      zz = __builtin_amdgcn_mfma_f32_16x16x32_bf16(
          qf[1], *(const sh8*)&Ks[k * 64 + (((4 + quad) ^ (k & 7)) * 8)], zz, 0, 0, 0);
      const int cg = kt * 64 + ct * 16 + ln;
      #pragma unroll
      for (int rr = 0; rr < 4; rr++) {
        float e = exp2f(fmaf(zz[rr], 0.18033688011112042f, -5.770780163555853f));
        if (diag && cg > rbase + rr) e = 0.0f;
        lpart[rr] += e;
        Psw[(quad * 4 + rr) * 72 + ct * 16 + ln] = f2b(e);
      }
    }

    #pragma unroll
    for (int kk = 0; kk < 2; kk++) {
      sh8 pf = *(const sh8*)&Psw[ln * 72 + kk * 32 + quad * 8];
      #pragma unroll
      for (int c2 = 0; c2 < 4; c2++) {
        const int d = c2 * 16 + ln;
        sh8 vf = *(const sh8*)&Vs[d * 64 + ((((kk * 4 + quad) ^ (d & 7))) * 8)];
        o[c2] = __builtin_amdgcn_mfma_f32_16x16x32_bf16(pf, vf, o[c2], 0, 0, 0);
      }
    }
  };

  // key-tiles of parity z (diagonal tile has parity qt&1)
  for (int kt = z; kt < qt; kt += 2) tile(kt, false);
  if ((qt & 1) == z) tile(qt, true);

  #pragma unroll
  for (int rr = 0; rr < 4; rr++) {
    #pragma unroll
    for (int off = 1; off < 16; off <<= 1) lpart[rr] += __shfl_xor(lpart[rr], off);
  }

  unsigned short* P = z ? p1 : p0;
  float* L = z ? l1 : l0;
  if (ln == 0) {
    #pragma unroll
    for (int rr = 0; rr < 4; rr++)
      L[((size_t)bh << 11) + q0 + w * 16 + quad * 4 + rr] = lpart[rr];
  }
  #pragma unroll
  for (int rr = 0; rr < 4; rr++) {
    const int row = q0 + w * 16 + quad * 4 + rr;
    const size_t base = ((size_t)b * SEQ + row) * D_MODEL + h * HD;
    #pragma unroll
    for (int c2 = 0; c2 < 4; c2++)
      P[base + c2 * 16 + ln] = f2b(o[c2][rr]);
  }
}

extern "C" void kernel_launch(void* const* d_in, const int* in_sizes, int n_in,
                              void* d_out, int out_size, void* d_ws, size_t ws_size,
                              hipStream_t stream) {
  const float* x    = (const float*)d_in[0];
  const float* Wq   = (const float*)d_in[1];
  const float* Wk   = (const float*)d_in[2];
  const float* Wv   = (const float*)d_in[3];
  const float* Wo   = (const float*)d_in[4];
  const float* Wup  = (const float*)d_in[5];
  const float* Wdn  = (const float*)d_in[6];
  const float* ln1m = (const float*)d_in[7];
  const float* ln1s = (const float*)d_in[8];
  const float* ln2m = (const float*)d_in[9];
  const float* ln2s = (const float*)d_in[10];
  float* out = (float*)d_out;

  unsigned short* ws = (unsigned short*)d_ws;
  size_t off = 0;
  unsigned short* wqkv = ws + off; off += (size_t)3072 * 1024;
  unsigned short* wo   = ws + off; off += (size_t)1024 * 1024;
  unsigned short* wup  = ws + off; off += (size_t)4096 * 1024;
  unsigned short* wdn  = ws + off; off += (size_t)1024 * 4096;
  unsigned short* xln  = ws + off; off += (size_t)NTOK * 1024;
  unsigned short* qkvb = ws + off; off += (size_t)NTOK * 3072;
  unsigned short* pre  = ws + off; off += (size_t)NTOK * 1024;
  unsigned short* mid  = qkvb;   // up-GEMM out [4096][4096] spans qkvb+pre exactly
  unsigned short* vtg  = xln;    // V^T aliases xln during attention (dead until LN2)
  unsigned short* po0  = qkvb;   // O-proj partials (qkvb dead after attn)
  unsigned short* po1  = qkvb + (size_t)NTOK * 1024;
  unsigned short* pd0  = ws;     // down partial 0: wqkv+wo region (weights dead)
  unsigned short* pd1  = xln;    // down partial 1 (NOT pre: pre aliases mid rows)
  // attention split-key scratch:
  unsigned short* ap1  = (unsigned short*)out;     // partial O (z=1); out dead until reduce_ln
  float* al0 = (float*)wqkv;                       // row-sums: wqkv region dead after QKV gemm
  float* al1 = al0 + (size_t)2 * NH * SEQ;

  // fused weight casts (12288 blocks x 1024 elems)
  cast6_kernel<<<12288, 256, 0, stream>>>(Wq, Wk, Wv, Wo, Wup, Wdn,
      wqkv, wqkv + (size_t)1024 * 1024, wqkv + (size_t)2 * 1024 * 1024, wo, wup, wdn);

  // LN1
  ln_kernel<<<NTOK, 256, 0, stream>>>(x, ln1m, ln1s, xln);
  // fused QKV projection: logical 24x32, XCD rect 12x8 (2x4 rects)
  gemm_nt<0, 24, 32, 1, 12, 8><<<768, 256, 0, stream>>>(xln, wqkv, 3072, 1024, 1024, qkvb, nullptr);
  // V transpose (xln region becomes vtg)
  vtrans_kernel<<<dim3(32, 32), 256, 0, stream>>>(qkvb, vtg);
  // causal flash attention, split-key z=2, XCD-swizzled grid (bh fastest)
  attn_kernel<<<dim3(2 * NH, SEQ / 64, 2), 256, 0, stream>>>(qkvb, vtg, pre, ap1, al0, al1);
  // combine: pre = (pre + ap1) / (al0 + al1)
  attn_combine_kernel<<<4096, 256, 0, stream>>>(pre, ap1, al0, al1);
  // O-projection: logical 8x32x2, XCD rect 4x16 (2x2x2 rects), split-K=2
  gemm_nt<0, 8, 32, 2, 4, 16><<<512, 256, 0, stream>>>(pre, wo, 1024, 1024, 512, po0, po1);
  // fused: out = x + po0 + po1 ; xln = LN2(out)
  reduce_ln_kernel<<<NTOK, 256, 0, stream>>>(po0, po1, x, ln2m, ln2s, out, xln);
  // MLP up + exp2-GELU: logical 32x32, XCD rect 8x16 (4x2 rects)
  gemm_nt<1, 32, 32, 1, 8, 16><<<1024, 256, 0, stream>>>(xln, wup, 4096, 1024, 1024, mid, nullptr);
  // MLP down: logical 8x32x2, XCD rect 8x8 (1x4x2 rects), split-K=2
  gemm_nt<0, 8, 32, 2, 8, 8><<<512, 256, 0, stream>>>(mid, wdn, 1024, 4096, 2048, pd0, pd1);
  // out += pd0 + pd1
  reduce2_kernel<<<4096, 256, 0, stream>>>(pd0, pd1, out);
}

// Round 9
// 350.489 us; speedup vs baseline: 1.0156x; 1.0098x over previous
//
#include <hip/hip_runtime.h>
#include <hip/hip_bf16.h>
#include <cstdint>
#include <cstddef>

#define D_MODEL 1024
#define SEQ     2048
#define NTOK    4096   // B*S
#define NH      16
#define HD      64

typedef __attribute__((ext_vector_type(8))) short sh8;
typedef __attribute__((ext_vector_type(4))) float f32x4;

#define GLL(g, s) __builtin_amdgcn_global_load_lds(                                   \
    (const __attribute__((address_space(1))) void*)(g),                               \
    (__attribute__((address_space(3))) void*)(s), 16, 0, 0)

__device__ __forceinline__ unsigned short f2b(float f) {
  union { float f; unsigned u; } v; v.f = f;
  unsigned r = v.u + 0x7FFFu + ((v.u >> 16) & 1u);
  return (unsigned short)(r >> 16);
}
__device__ __forceinline__ float b2f(unsigned short h) {
  union { unsigned u; float f; } v; v.u = ((unsigned)h) << 16;
  return v.f;
}

// ------- fused: fp32->bf16 cast for all 6 weights (blocks 0..12287) + LN1
// ------- (blocks 12288..16383).  Both memory-bound & independent.
__global__ __launch_bounds__(256) void castln_kernel(
    const float* __restrict__ q, const float* __restrict__ k, const float* __restrict__ v,
    const float* __restrict__ o, const float* __restrict__ u, const float* __restrict__ d,
    unsigned short* __restrict__ oq, unsigned short* __restrict__ ok,
    unsigned short* __restrict__ ov, unsigned short* __restrict__ oo,
    unsigned short* __restrict__ ou, unsigned short* __restrict__ od,
    const float* __restrict__ x, const float* __restrict__ msc,
    const float* __restrict__ ssc, unsigned short* __restrict__ xout) {
  const int bid = blockIdx.x;
  const int tid = threadIdx.x;
  __shared__ float sh[8];
  if (bid < 12288) {
    const float* src; unsigned short* dst; int base;
    if      (bid < 1024) { src = q; dst = oq; base = bid; }
    else if (bid < 2048) { src = k; dst = ok; base = bid - 1024; }
    else if (bid < 3072) { src = v; dst = ov; base = bid - 2048; }
    else if (bid < 4096) { src = o; dst = oo; base = bid - 3072; }
    else if (bid < 8192) { src = u; dst = ou; base = bid - 4096; }
    else                 { src = d; dst = od; base = bid - 8192; }
    int i = base * 1024 + tid * 4;
    float4 vv = *(const float4*)(src + i);
    ushort4 w;
    w.x = f2b(vv.x); w.y = f2b(vv.y); w.z = f2b(vv.z); w.w = f2b(vv.w);
    *(ushort4*)(dst + i) = w;
    return;
  }
  const int t = bid - 12288;
  const float4 vv = ((const float4*)(x + (size_t)t * D_MODEL))[tid];
  float s = vv.x + vv.y + vv.z + vv.w;
  float qs = vv.x * vv.x + vv.y * vv.y + vv.z * vv.z + vv.w * vv.w;
  #pragma unroll
  for (int off = 32; off; off >>= 1) {
    s += __shfl_xor(s, off);
    qs += __shfl_xor(qs, off);
  }
  const int w = tid >> 6;
  if ((tid & 63) == 0) { sh[w * 2] = s; sh[w * 2 + 1] = qs; }
  __syncthreads();
  s = sh[0] + sh[2] + sh[4] + sh[6];
  qs = sh[1] + sh[3] + sh[5] + sh[7];
  const float mean = s * (1.0f / D_MODEL);
  const float var = (qs - (float)D_MODEL * mean * mean) * (1.0f / (D_MODEL - 1));
  const float rstd = rsqrtf(var + 1e-9f);
  const float4 ms = ((const float4*)msc)[tid];
  const float4 ss = ((const float4*)ssc)[tid];
  ushort4 oo4;
  oo4.x = f2b((vv.x - mean) * rstd * ss.x + ms.x);
  oo4.y = f2b((vv.y - mean) * rstd * ss.y + ms.y);
  oo4.z = f2b((vv.z - mean) * rstd * ss.z + ms.z);
  oo4.w = f2b((vv.w - mean) * rstd * ss.w + ms.w);
  ((ushort4*)(xout + (size_t)t * D_MODEL))[tid] = oo4;
}

// -------- fused: out = x + p0 + p1 ; oln = LN2(out) (one pass per row) --------
__global__ __launch_bounds__(256) void reduce_ln_kernel(
    const unsigned short* __restrict__ p0, const unsigned short* __restrict__ p1,
    const float* __restrict__ x, const float* __restrict__ msc,
    const float* __restrict__ ssc, float* __restrict__ out,
    unsigned short* __restrict__ oln) {
  const int t = blockIdx.x;
  const int tid = threadIdx.x;
  const size_t base = (size_t)t * D_MODEL + tid * 4;
  ushort4 a = *(const ushort4*)(p0 + base);
  ushort4 b = *(const ushort4*)(p1 + base);
  float4 xv = *(const float4*)(x + base);
  float4 r;
  r.x = xv.x + b2f(a.x) + b2f(b.x);
  r.y = xv.y + b2f(a.y) + b2f(b.y);
  r.z = xv.z + b2f(a.z) + b2f(b.z);
  r.w = xv.w + b2f(a.w) + b2f(b.w);
  *(float4*)(out + base) = r;
  float s = r.x + r.y + r.z + r.w;
  float q = r.x * r.x + r.y * r.y + r.z * r.z + r.w * r.w;
  #pragma unroll
  for (int off = 32; off; off >>= 1) {
    s += __shfl_xor(s, off);
    q += __shfl_xor(q, off);
  }
  __shared__ float sh[8];
  const int w = tid >> 6;
  if ((tid & 63) == 0) { sh[w * 2] = s; sh[w * 2 + 1] = q; }
  __syncthreads();
  s = sh[0] + sh[2] + sh[4] + sh[6];
  q = sh[1] + sh[3] + sh[5] + sh[7];
  const float mean = s * (1.0f / D_MODEL);
  const float var = (q - (float)D_MODEL * mean * mean) * (1.0f / (D_MODEL - 1));
  const float rstd = rsqrtf(var + 1e-9f);
  const float4 ms = ((const float4*)msc)[tid];
  const float4 ss = ((const float4*)ssc)[tid];
  ushort4 o;
  o.x = f2b((r.x - mean) * rstd * ss.x + ms.x);
  o.y = f2b((r.y - mean) * rstd * ss.y + ms.y);
  o.z = f2b((r.z - mean) * rstd * ss.z + ms.z);
  o.w = f2b((r.w - mean) * rstd * ss.w + ms.w);
  *(ushort4*)(oln + base) = o;
}

// ---------------- attention split-key combine: pre = (p0+p1)/(l0+l1) ----------
__global__ __launch_bounds__(256) void attn_combine_kernel(
    unsigned short* __restrict__ p0, const unsigned short* __restrict__ p1,
    const float* __restrict__ l0, const float* __restrict__ l1) {
  int i = (blockIdx.x * 256 + threadIdx.x) * 4;
  const int tok = i >> 10, ch = i & 1023;
  const int b = tok >> 11, s = tok & 2047, h = ch >> 6;
  const int lidx = ((b << 4) + h) * 2048 + s;
  const float inv = 1.0f / (l0[lidx] + l1[lidx]);
  ushort4 a = *(const ushort4*)(p0 + i);
  ushort4 c = *(const ushort4*)(p1 + i);
  ushort4 r;
  r.x = f2b((b2f(a.x) + b2f(c.x)) * inv);
  r.y = f2b((b2f(a.y) + b2f(c.y)) * inv);
  r.z = f2b((b2f(a.z) + b2f(c.z)) * inv);
  r.w = f2b((b2f(a.w) + b2f(c.w)) * inv);
  *(ushort4*)(p0 + i) = r;
}

// ---------------- V transpose: qkv[tok][2048+d] -> vt[b][d][s] ----------------
__global__ __launch_bounds__(256) void vtrans_kernel(const unsigned short* __restrict__ qkv,
                                                     unsigned short* __restrict__ vt) {
  __shared__ unsigned short T[64][72];
  const int st = blockIdx.x;            // s-tile 0..31
  const int b  = blockIdx.y >> 4;
  const int dt = blockIdx.y & 15;       // d-tile 0..15
  const int tid = threadIdx.x;
  const int s0 = st * 64, d0 = dt * 64;
  const int r = tid >> 2, c0 = (tid & 3) * 16;
  const unsigned short* src = qkv + ((size_t)b * SEQ + s0 + r) * 3072 + 2 * D_MODEL + d0 + c0;
  *(uint4*)&T[r][c0]     = *(const uint4*)(src);
  *(uint4*)&T[r][c0 + 8] = *(const uint4*)(src + 8);
  __syncthreads();
  unsigned short buf[16] __attribute__((aligned(16)));
  #pragma unroll
  for (int j = 0; j < 16; j++) buf[j] = T[c0 + j][r];
  unsigned short* dst = vt + ((size_t)b * D_MODEL + d0 + r) * SEQ + s0 + c0;
  *(uint4*)(dst)     = *(uint4*)&buf[0];
  *(uint4*)(dst + 8) = *(uint4*)&buf[8];
}

// =====================================================================
// 128x128 NT GEMM (R5 proven): BK=64, 4 waves (2x2), single-buffered
// 32KB LDS, GLL staging, XOR chunk swizzle, bijective XCD rect remap.
// Epilogue: column-coalesced scalar stores (ln-indexed gn).
// EP: 0 = bf16 store, 1 = exp2-GELU bf16 store.
// =====================================================================
template <int EP, int GX, int GY, int GZ, int CHX, int CHY>
__global__ __launch_bounds__(256) void gemm_nt(const unsigned short* __restrict__ A,
                                               const unsigned short* __restrict__ B,
                                               int N, int LD, int Kext,
                                               unsigned short* __restrict__ Cbf,
                                               unsigned short* __restrict__ Cbf2) {
  constexpr int NRX = GX / CHX;
  constexpr int NRY = GY / CHY;
  static_assert(NRX * NRY * GZ == 8, "rect count must equal 8 XCDs");
  __shared__ __align__(16) unsigned short As[128 * 64];
  __shared__ __align__(16) unsigned short Bs[128 * 64];
  const int tid = threadIdx.x;
  const int w = tid >> 6, l = tid & 63, ln = tid & 15, quad = (tid & 63) >> 4;
  const int wr = (w >> 1) * 64, wc = (w & 1) * 64;

  // XCD-locality remap: physical block l%8 -> XCD l%8 owns rect #(l%8)
  const int lb  = blockIdx.x;
  const int xcd = lb & 7, slot = lb >> 3;
  const int rx  = xcd % NRX, rem = xcd / NRX;
  const int ry  = rem % NRY, rz = rem / NRY;
  const int sx  = slot % CHX, sy = slot / CHX;
  const int bx  = rx * CHX + sx;
  const int by  = ry * CHY + sy;
  const int bz  = rz;

  const int m0 = by * 128, n0 = bx * 128;
  const int koff = bz * Kext;

  const int sr = l >> 3, sc = l & 7;
  const unsigned short* AgS = A + (size_t)(m0 + w * 32 + sr) * LD + koff + ((sc ^ sr) * 8);
  const unsigned short* BgS = B + (size_t)(n0 + w * 32 + sr) * LD + koff + ((sc ^ sr) * 8);
  unsigned short* AsW = &As[(w * 32) * 64];
  unsigned short* BsW = &Bs[(w * 32) * 64];

  f32x4 acc[4][4] = {};

  for (int k0 = 0; k0 < Kext; k0 += 64) {
    __syncthreads();
    #pragma unroll
    for (int off = 0; off < 32; off += 8) {
      GLL(AgS + k0 + (size_t)off * LD, AsW + off * 64);
      GLL(BgS + k0 + (size_t)off * LD, BsW + off * 64);
    }
    __syncthreads();
    sh8 af[2][4], bfr[2][4];
    #pragma unroll
    for (int kk = 0; kk < 2; kk++) {
      #pragma unroll
      for (int i = 0; i < 4; i++)
        af[kk][i]  = *(const sh8*)&As[(wr + i * 16 + ln) * 64 + (((kk * 4 + quad) ^ (ln & 7)) * 8)];
      #pragma unroll
      for (int j = 0; j < 4; j++)
        bfr[kk][j] = *(const sh8*)&Bs[(wc + j * 16 + ln) * 64 + (((kk * 4 + quad) ^ (ln & 7)) * 8)];
    }
    #pragma unroll
    for (int kk = 0; kk < 2; kk++)
      #pragma unroll
      for (int i = 0; i < 4; i++)
        #pragma unroll
        for (int j = 0; j < 4; j++)
          acc[i][j] = __builtin_amdgcn_mfma_f32_16x16x32_bf16(af[kk][i], bfr[kk][j], acc[i][j], 0, 0, 0);
  }

  unsigned short* C = bz ? Cbf2 : Cbf;
  #pragma unroll
  for (int i = 0; i < 4; i++) {
    #pragma unroll
    for (int rr = 0; rr < 4; rr++) {
      const int gm = m0 + wr + i * 16 + quad * 4 + rr;
      #pragma unroll
      for (int j = 0; j < 4; j++) {
        const int gn = n0 + wc + j * 16 + ln;
        float v = acc[i][j][rr];
        if (EP == 1) {
          // tanh-form GELU via exp2: g = v*e/(e+1), e = 2^(2.30219*(v+0.044715 v^3))
          const float vc = fminf(v, 8.0f);
          const float e = exp2f(2.3021906f * fmaf(0.044715f * vc * vc, vc, vc));
          v = v * e / (e + 1.0f);
        }
        C[(size_t)gm * N + gn] = f2b(v);
      }
    }
  }
}

// =====================================================================
// Standalone down-projection GEMM (NOT a gemm_nt instantiation — keeps
// gemm_nt<0/1> codegen identical to R5, per rule #19).  Same body/tile;
// epilogue atomically folds f32 partials into out (= x + attn, written
// by reduce_ln, stream-ordered before this kernel).  Split-K=2 -> each
// output gets exactly 2 atomic adds.  Eliminates reduce2 (~50MB + launch).
// Shape fixed: A=mid[4096][4096], B=wdn[1024][4096], C=out f32 [4096][1024].
// Grid 512: logical 8x32x2, XCD rect 8x8 (1x4x2 rects).
// =====================================================================
__global__ __launch_bounds__(256) void gemm_dn(const unsigned short* __restrict__ A,
                                               const unsigned short* __restrict__ B,
                                               float* __restrict__ out) {
  constexpr int N = 1024, LD = 4096, Kext = 2048;
  constexpr int NRX = 1, NRY = 4, CHX = 8, CHY = 8;
  __shared__ __align__(16) unsigned short As[128 * 64];
  __shared__ __align__(16) unsigned short Bs[128 * 64];
  const int tid = threadIdx.x;
  const int w = tid >> 6, l = tid & 63, ln = tid & 15, quad = (tid & 63) >> 4;
  const int wr = (w >> 1) * 64, wc = (w & 1) * 64;

  const int lb  = blockIdx.x;
  const int xcd = lb & 7, slot = lb >> 3;
  const int rx  = xcd % NRX, rem = xcd / NRX;
  const int ry  = rem % NRY, rz = rem / NRY;
  const int sx  = slot % CHX, sy = slot / CHX;
  const int bx  = rx * CHX + sx;
  const int by  = ry * CHY + sy;
  const int bz  = rz;

  const int m0 = by * 128, n0 = bx * 128;
  const int koff = bz * Kext;

  const int sr = l >> 3, sc = l & 7;
  const unsigned short* AgS = A + (size_t)(m0 + w * 32 + sr) * LD + koff + ((sc ^ sr) * 8);
  const unsigned short* BgS = B + (size_t)(n0 + w * 32 + sr) * LD + koff + ((sc ^ sr) * 8);
  unsigned short* AsW = &As[(w * 32) * 64];
  unsigned short* BsW = &Bs[(w * 32) * 64];

  f32x4 acc[4][4] = {};

  for (int k0 = 0; k0 < Kext; k0 += 64) {
    __syncthreads();
    #pragma unroll
    for (int off = 0; off < 32; off += 8) {
      GLL(AgS + k0 + (size_t)off * LD, AsW + off * 64);
      GLL(BgS + k0 + (size_t)off * LD, BsW + off * 64);
    }
    __syncthreads();
    sh8 af[2][4], bfr[2][4];
    #pragma unroll
    for (int kk = 0; kk < 2; kk++) {
      #pragma unroll
      for (int i = 0; i < 4; i++)
        af[kk][i]  = *(const sh8*)&As[(wr + i * 16 + ln) * 64 + (((kk * 4 + quad) ^ (ln & 7)) * 8)];
      #pragma unroll
      for (int j = 0; j < 4; j++)
        bfr[kk][j] = *(const sh8*)&Bs[(wc + j * 16 + ln) * 64 + (((kk * 4 + quad) ^ (ln & 7)) * 8)];
    }
    #pragma unroll
    for (int kk = 0; kk < 2; kk++)
      #pragma unroll
      for (int i = 0; i < 4; i++)
        #pragma unroll
        for (int j = 0; j < 4; j++)
          acc[i][j] = __builtin_amdgcn_mfma_f32_16x16x32_bf16(af[kk][i], bfr[kk][j], acc[i][j], 0, 0, 0);
  }

  #pragma unroll
  for (int i = 0; i < 4; i++) {
    #pragma unroll
    for (int rr = 0; rr < 4; rr++) {
      const int gm = m0 + wr + i * 16 + quad * 4 + rr;
      #pragma unroll
      for (int j = 0; j < 4; j++) {
        const int gn = n0 + wc + j * 16 + ln;
        unsafeAtomicAdd(out + (size_t)gm * N + gn, acc[i][j][rr]);
      }
    }
  }
}

// ---------------- Flash attention, causal, BM=64, BN=64, fixed-max softmax ----
__global__ __launch_bounds__(256) void attn_kernel(const unsigned short* __restrict__ qkv,
                                                   const unsigned short* __restrict__ vt,
                                                   unsigned short* __restrict__ p0,
                                                   unsigned short* __restrict__ p1,
                                                   float* __restrict__ l0,
                                                   float* __restrict__ l1) {
  const int bh = blockIdx.x;                    // XCD swizzle: bh fastest
  const int qt = (SEQ / 64 - 1) - blockIdx.y;   // reversed: long blocks first
  const int z  = blockIdx.z;
  const int b = bh >> 4, h = bh & 15;
  const int tid = threadIdx.x;
  const int w = tid >> 6, l = tid & 63, ln = tid & 15, quad = (tid & 63) >> 4;
  const int q0 = qt * 64;

  __shared__ __align__(16) unsigned short Ks[64 * 64];   // [key][d], chunk ^ (key&7)
  __shared__ __align__(16) unsigned short Vs[64 * 64];   // [d][key], chunk ^ (d&7)
  __shared__ __align__(16) unsigned short Ps[4][16 * 72];

  const size_t rstride = 3 * D_MODEL;
  const unsigned short* Qg = qkv + (size_t)b * SEQ * rstride + h * HD;
  const unsigned short* Kg = Qg + D_MODEL;
  const unsigned short* Vg = vt + ((size_t)b * D_MODEL + h * HD) * SEQ;

  sh8 qf[2];
  {
    const unsigned short* qrow = Qg + (size_t)(q0 + w * 16 + ln) * rstride + quad * 8;
    qf[0] = *(const sh8*)(qrow);
    qf[1] = *(const sh8*)(qrow + 32);
  }

  const int lr3 = l >> 3, lp3 = l & 7;
  const int cS = (lp3 ^ lr3) * 8;
  const unsigned short* KgS = Kg + (size_t)(w * 16 + lr3) * rstride + cS;
  unsigned short* KsW = &Ks[(w * 16) * 64];
  const unsigned short* VgS = Vg + (size_t)(w * 16 + lr3) * SEQ + cS;
  unsigned short* VsW = &Vs[(w * 16) * 64];
  unsigned short* Psw = &Ps[w][0];

  f32x4 o[4] = {};
  float lpart[4] = {0.f, 0.f, 0.f, 0.f};
  const int rbase = q0 + w * 16 + quad * 4;

  auto tile = [&](int kt, bool diag) {
    __syncthreads();
    GLL(KgS + (size_t)(kt * 64) * rstride,     KsW);
    GLL(KgS + (size_t)(kt * 64 + 8) * rstride, KsW + 8 * 64);
    GLL(VgS + kt * 64,           VsW);
    GLL(VgS + 8 * SEQ + kt * 64, VsW + 8 * 64);
    __syncthreads();

    #pragma unroll
    for (int ct = 0; ct < 4; ct++) {
      const int k = ct * 16 + ln;
      f32x4 zz = {};
      zz = __builtin_amdgcn_mfma_f32_16x16x32_bf16(
          qf[0], *(const sh8*)&Ks[k * 64 + ((quad ^ (k & 7)) * 8)], zz, 0, 0, 0);
      zz = __builtin_amdgcn_mfma_f32_16x16x32_bf16(
          qf[1], *(const sh8*)&Ks[k * 64 + (((4 + quad) ^ (k & 7)) * 8)], zz, 0, 0, 0);
      const int cg = kt * 64 + ct * 16 + ln;
      #pragma unroll
      for (int rr = 0; rr < 4; rr++) {
        float e = exp2f(fmaf(zz[rr], 0.18033688011112042f, -5.770780163555853f));
        if (diag && cg > rbase + rr) e = 0.0f;
        lpart[rr] += e;
        Psw[(quad * 4 + rr) * 72 + ct * 16 + ln] = f2b(e);
      }
    }

    #pragma unroll
    for (int kk = 0; kk < 2; kk++) {
      sh8 pf = *(const sh8*)&Psw[ln * 72 + kk * 32 + quad * 8];
      #pragma unroll
      for (int c2 = 0; c2 < 4; c2++) {
        const int d = c2 * 16 + ln;
        sh8 vf = *(const sh8*)&Vs[d * 64 + ((((kk * 4 + quad) ^ (d & 7))) * 8)];
        o[c2] = __builtin_amdgcn_mfma_f32_16x16x32_bf16(pf, vf, o[c2], 0, 0, 0);
      }
    }
  };

  // key-tiles of parity z (diagonal tile has parity qt&1)
  for (int kt = z; kt < qt; kt += 2) tile(kt, false);
  if ((qt & 1) == z) tile(qt, true);

  #pragma unroll
  for (int rr = 0; rr < 4; rr++) {
    #pragma unroll
    for (int off = 1; off < 16; off <<= 1) lpart[rr] += __shfl_xor(lpart[rr], off);
  }

  unsigned short* P = z ? p1 : p0;
  float* L = z ? l1 : l0;
  if (ln == 0) {
    #pragma unroll
    for (int rr = 0; rr < 4; rr++)
      L[((size_t)bh << 11) + q0 + w * 16 + quad * 4 + rr] = lpart[rr];
  }
  #pragma unroll
  for (int rr = 0; rr < 4; rr++) {
    const int row = q0 + w * 16 + quad * 4 + rr;
    const size_t base = ((size_t)b * SEQ + row) * D_MODEL + h * HD;
    #pragma unroll
    for (int c2 = 0; c2 < 4; c2++)
      P[base + c2 * 16 + ln] = f2b(o[c2][rr]);
  }
}

extern "C" void kernel_launch(void* const* d_in, const int* in_sizes, int n_in,
                              void* d_out, int out_size, void* d_ws, size_t ws_size,
                              hipStream_t stream) {
  const float* x    = (const float*)d_in[0];
  const float* Wq   = (const float*)d_in[1];
  const float* Wk   = (const float*)d_in[2];
  const float* Wv   = (const float*)d_in[3];
  const float* Wo   = (const float*)d_in[4];
  const float* Wup  = (const float*)d_in[5];
  const float* Wdn  = (const float*)d_in[6];
  const float* ln1m = (const float*)d_in[7];
  const float* ln1s = (const float*)d_in[8];
  const float* ln2m = (const float*)d_in[9];
  const float* ln2s = (const float*)d_in[10];
  float* out = (float*)d_out;

  unsigned short* ws = (unsigned short*)d_ws;
  size_t off = 0;
  unsigned short* wqkv = ws + off; off += (size_t)3072 * 1024;
  unsigned short* wo   = ws + off; off += (size_t)1024 * 1024;
  unsigned short* wup  = ws + off; off += (size_t)4096 * 1024;
  unsigned short* wdn  = ws + off; off += (size_t)1024 * 4096;
  unsigned short* xln  = ws + off; off += (size_t)NTOK * 1024;
  unsigned short* qkvb = ws + off; off += (size_t)NTOK * 3072;
  unsigned short* pre  = ws + off; off += (size_t)NTOK * 1024;
  unsigned short* mid  = qkvb;   // up-GEMM out [4096][4096] spans qkvb+pre exactly
  unsigned short* vtg  = xln;    // V^T aliases xln during attention (dead until LN2)
  unsigned short* po0  = qkvb;   // O-proj partials (qkvb dead after attn)
  unsigned short* po1  = qkvb + (size_t)NTOK * 1024;
  // attention split-key scratch:
  unsigned short* ap1  = (unsigned short*)out;     // partial O (z=1); out dead until reduce_ln
  float* al0 = (float*)wqkv;                       // row-sums: wqkv region dead after QKV gemm
  float* al1 = al0 + (size_t)2 * NH * SEQ;

  // fused weight casts + LN1 (12288 cast blocks + 4096 LN blocks)
  castln_kernel<<<16384, 256, 0, stream>>>(Wq, Wk, Wv, Wo, Wup, Wdn,
      wqkv, wqkv + (size_t)1024 * 1024, wqkv + (size_t)2 * 1024 * 1024, wo, wup, wdn,
      x, ln1m, ln1s, xln);

  // fused QKV projection: logical 24x32, XCD rect 12x8 (2x4 rects)
  gemm_nt<0, 24, 32, 1, 12, 8><<<768, 256, 0, stream>>>(xln, wqkv, 3072, 1024, 1024, qkvb, nullptr);
  // V transpose (xln region becomes vtg)
  vtrans_kernel<<<dim3(32, 32), 256, 0, stream>>>(qkvb, vtg);
  // causal flash attention, split-key z=2, XCD-swizzled grid (bh fastest)
  attn_kernel<<<dim3(2 * NH, SEQ / 64, 2), 256, 0, stream>>>(qkvb, vtg, pre, ap1, al0, al1);
  // combine: pre = (pre + ap1) / (al0 + al1)
  attn_combine_kernel<<<4096, 256, 0, stream>>>(pre, ap1, al0, al1);
  // O-projection: logical 8x32x2, XCD rect 4x16 (2x2x2 rects), split-K=2
  gemm_nt<0, 8, 32, 2, 4, 16><<<512, 256, 0, stream>>>(pre, wo, 1024, 1024, 512, po0, po1);
  // fused: out = x + po0 + po1 ; xln = LN2(out)
  reduce_ln_kernel<<<NTOK, 256, 0, stream>>>(po0, po1, x, ln2m, ln2s, out, xln);
  // MLP up + exp2-GELU: logical 32x32, XCD rect 8x16 (4x2 rects)
  gemm_nt<1, 32, 32, 1, 8, 16><<<1024, 256, 0, stream>>>(xln, wup, 4096, 1024, 1024, mid, nullptr);
  // MLP down: standalone kernel, split-K=2, f32 atomic fold into out (no reduce2)
  gemm_dn<<<512, 256, 0, stream>>>(mid, wdn, out);
}

// Round 10
// 330.897 us; speedup vs baseline: 1.0758x; 1.0592x over previous
//
#include <hip/hip_runtime.h>
#include <hip/hip_bf16.h>
#include <cstdint>
#include <cstddef>

#define D_MODEL 1024
#define SEQ     2048
#define NTOK    4096   // B*S
#define NH      16
#define HD      64

typedef __attribute__((ext_vector_type(8))) short sh8;
typedef __attribute__((ext_vector_type(4))) float f32x4;
typedef __attribute__((ext_vector_type(16))) float f32x16;

#define GLL(g, s) __builtin_amdgcn_global_load_lds(                                   \
    (const __attribute__((address_space(1))) void*)(g),                               \
    (__attribute__((address_space(3))) void*)(s), 16, 0, 0)

__device__ __forceinline__ unsigned short f2b(float f) {
  union { float f; unsigned u; } v; v.f = f;
  unsigned r = v.u + 0x7FFFu + ((v.u >> 16) & 1u);
  return (unsigned short)(r >> 16);
}
__device__ __forceinline__ float b2f(unsigned short h) {
  union { unsigned u; float f; } v; v.u = ((unsigned)h) << 16;
  return v.f;
}

// ---------------- fused fp32 -> bf16 cast for all 6 weights ----------------
__global__ __launch_bounds__(256) void cast6_kernel(
    const float* __restrict__ q, const float* __restrict__ k, const float* __restrict__ v,
    const float* __restrict__ o, const float* __restrict__ u, const float* __restrict__ d,
    unsigned short* __restrict__ oq, unsigned short* __restrict__ ok,
    unsigned short* __restrict__ ov, unsigned short* __restrict__ oo,
    unsigned short* __restrict__ ou, unsigned short* __restrict__ od) {
  int bid = blockIdx.x;
  const float* src; unsigned short* dst; int base;
  if      (bid < 1024) { src = q; dst = oq; base = bid; }
  else if (bid < 2048) { src = k; dst = ok; base = bid - 1024; }
  else if (bid < 3072) { src = v; dst = ov; base = bid - 2048; }
  else if (bid < 4096) { src = o; dst = oo; base = bid - 3072; }
  else if (bid < 8192) { src = u; dst = ou; base = bid - 4096; }
  else                 { src = d; dst = od; base = bid - 8192; }
  int i = base * 1024 + threadIdx.x * 4;
  float4 vv = *(const float4*)(src + i);
  ushort4 w;
  w.x = f2b(vv.x); w.y = f2b(vv.y); w.z = f2b(vv.z); w.w = f2b(vv.w);
  *(ushort4*)(dst + i) = w;
}

// ---------------- LayerNorm (torch var ddof=1), bf16 out ----------------
__global__ __launch_bounds__(256) void ln_kernel(const float* __restrict__ x,
                                                 const float* __restrict__ msc,
                                                 const float* __restrict__ ssc,
                                                 unsigned short* __restrict__ out) {
  const int t = blockIdx.x;
  const int tid = threadIdx.x;
  const float4 v = ((const float4*)(x + (size_t)t * D_MODEL))[tid];
  float s = v.x + v.y + v.z + v.w;
  float q = v.x * v.x + v.y * v.y + v.z * v.z + v.w * v.w;
  #pragma unroll
  for (int off = 32; off; off >>= 1) {
    s += __shfl_xor(s, off);
    q += __shfl_xor(q, off);
  }
  __shared__ float sh[8];
  const int w = tid >> 6;
  if ((tid & 63) == 0) { sh[w * 2] = s; sh[w * 2 + 1] = q; }
  __syncthreads();
  s = sh[0] + sh[2] + sh[4] + sh[6];
  q = sh[1] + sh[3] + sh[5] + sh[7];
  const float mean = s * (1.0f / D_MODEL);
  const float var = (q - (float)D_MODEL * mean * mean) * (1.0f / (D_MODEL - 1));
  const float rstd = rsqrtf(var + 1e-9f);
  const float4 ms = ((const float4*)msc)[tid];
  const float4 ss = ((const float4*)ssc)[tid];
  ushort4 o;
  o.x = f2b((v.x - mean) * rstd * ss.x + ms.x);
  o.y = f2b((v.y - mean) * rstd * ss.y + ms.y);
  o.z = f2b((v.z - mean) * rstd * ss.z + ms.z);
  o.w = f2b((v.w - mean) * rstd * ss.w + ms.w);
  ((ushort4*)(out + (size_t)t * D_MODEL))[tid] = o;
}

// -------- fused: out = x + p0 + p1 ; oln = LN2(out) (one pass per row) --------
__global__ __launch_bounds__(256) void reduce_ln_kernel(
    const unsigned short* __restrict__ p0, const unsigned short* __restrict__ p1,
    const float* __restrict__ x, const float* __restrict__ msc,
    const float* __restrict__ ssc, float* __restrict__ out,
    unsigned short* __restrict__ oln) {
  const int t = blockIdx.x;
  const int tid = threadIdx.x;
  const size_t base = (size_t)t * D_MODEL + tid * 4;
  ushort4 a = *(const ushort4*)(p0 + base);
  ushort4 b = *(const ushort4*)(p1 + base);
  float4 xv = *(const float4*)(x + base);
  float4 r;
  r.x = xv.x + b2f(a.x) + b2f(b.x);
  r.y = xv.y + b2f(a.y) + b2f(b.y);
  r.z = xv.z + b2f(a.z) + b2f(b.z);
  r.w = xv.w + b2f(a.w) + b2f(b.w);
  *(float4*)(out + base) = r;
  float s = r.x + r.y + r.z + r.w;
  float q = r.x * r.x + r.y * r.y + r.z * r.z + r.w * r.w;
  #pragma unroll
  for (int off = 32; off; off >>= 1) {
    s += __shfl_xor(s, off);
    q += __shfl_xor(q, off);
  }
  __shared__ float sh[8];
  const int w = tid >> 6;
  if ((tid & 63) == 0) { sh[w * 2] = s; sh[w * 2 + 1] = q; }
  __syncthreads();
  s = sh[0] + sh[2] + sh[4] + sh[6];
  q = sh[1] + sh[3] + sh[5] + sh[7];
  const float mean = s * (1.0f / D_MODEL);
  const float var = (q - (float)D_MODEL * mean * mean) * (1.0f / (D_MODEL - 1));
  const float rstd = rsqrtf(var + 1e-9f);
  const float4 ms = ((const float4*)msc)[tid];
  const float4 ss = ((const float4*)ssc)[tid];
  ushort4 o;
  o.x = f2b((r.x - mean) * rstd * ss.x + ms.x);
  o.y = f2b((r.y - mean) * rstd * ss.y + ms.y);
  o.z = f2b((r.z - mean) * rstd * ss.z + ms.z);
  o.w = f2b((r.w - mean) * rstd * ss.w + ms.w);
  *(ushort4*)(oln + base) = o;
}

// ---------------- split-K partial reduce: out += p0 + p1 ----------------------
__global__ __launch_bounds__(256) void reduce2_kernel(const unsigned short* __restrict__ p0,
                                                      const unsigned short* __restrict__ p1,
                                                      float* __restrict__ out) {
  int i = (blockIdx.x * 256 + threadIdx.x) * 4;
  ushort4 a = *(const ushort4*)(p0 + i);
  ushort4 b = *(const ushort4*)(p1 + i);
  float4 base = *(const float4*)(out + i);
  float4 r;
  r.x = base.x + b2f(a.x) + b2f(b.x);
  r.y = base.y + b2f(a.y) + b2f(b.y);
  r.z = base.z + b2f(a.z) + b2f(b.z);
  r.w = base.w + b2f(a.w) + b2f(b.w);
  *(float4*)(out + i) = r;
}

// ---------------- attention split-key combine: pre = (p0+p1)/(l0+l1) ----------
__global__ __launch_bounds__(256) void attn_combine_kernel(
    unsigned short* __restrict__ p0, const unsigned short* __restrict__ p1,
    const float* __restrict__ l0, const float* __restrict__ l1) {
  int i = (blockIdx.x * 256 + threadIdx.x) * 4;
  const int tok = i >> 10, ch = i & 1023;
  const int b = tok >> 11, s = tok & 2047, h = ch >> 6;
  const int lidx = ((b << 4) + h) * 2048 + s;
  const float inv = 1.0f / (l0[lidx] + l1[lidx]);
  ushort4 a = *(const ushort4*)(p0 + i);
  ushort4 c = *(const ushort4*)(p1 + i);
  ushort4 r;
  r.x = f2b((b2f(a.x) + b2f(c.x)) * inv);
  r.y = f2b((b2f(a.y) + b2f(c.y)) * inv);
  r.z = f2b((b2f(a.z) + b2f(c.z)) * inv);
  r.w = f2b((b2f(a.w) + b2f(c.w)) * inv);
  *(ushort4*)(p0 + i) = r;
}

// ---------------- V transpose: qkv[tok][2048+d] -> vt[b][d][s] ----------------
__global__ __launch_bounds__(256) void vtrans_kernel(const unsigned short* __restrict__ qkv,
                                                     unsigned short* __restrict__ vt) {
  __shared__ unsigned short T[64][72];
  const int st = blockIdx.x;            // s-tile 0..31
  const int b  = blockIdx.y >> 4;
  const int dt = blockIdx.y & 15;       // d-tile 0..15
  const int tid = threadIdx.x;
  const int s0 = st * 64, d0 = dt * 64;
  const int r = tid >> 2, c0 = (tid & 3) * 16;
  const unsigned short* src = qkv + ((size_t)b * SEQ + s0 + r) * 3072 + 2 * D_MODEL + d0 + c0;
  *(uint4*)&T[r][c0]     = *(const uint4*)(src);
  *(uint4*)&T[r][c0 + 8] = *(const uint4*)(src + 8);
  __syncthreads();
  unsigned short buf[16] __attribute__((aligned(16)));
  #pragma unroll
  for (int j = 0; j < 16; j++) buf[j] = T[c0 + j][r];
  unsigned short* dst = vt + ((size_t)b * D_MODEL + d0 + r) * SEQ + s0 + c0;
  *(uint4*)(dst)     = *(uint4*)&buf[0];
  *(uint4*)(dst + 8) = *(uint4*)&buf[8];
}

// =====================================================================
// 128x128 NT GEMM — R10: 32x32x16 MFMA (half the MFMA instructions per
// FLOP vs 16x16x32; 2495 vs 2075 TF ubench ceiling).  BK=64, 4 waves
// (2x2, 64x64 per wave = 2x2 frags of 32x32), single-buffered LDS with
// GLL staging.  LDS rows stored in 8-row GROUPS with 16B pad between
// groups (group stride 1040B): keeps each GLL's 1KB dest contiguous
// while de-aliasing rows r,r+8,r+16,r+24 (+4 banks per group) so the
// 32-row fragment reads stay at the structural LDS floor.
// XOR chunk swizzle within a group (same involution as R5, via
// pre-swizzled global source).  Bijective XCD rect remap.
// A-frag: lane l holds A[m=l&31][k=(l>>5)*8+r]; B-frag symmetric
// (k-mapping errors cancel if A/B consistent).  C/D (HW-verified m74):
// col=l&31, row=(reg&3)+8*(reg>>2)+4*(l>>5).
// EP: 0 = bf16 store, 1 = exp2-GELU bf16 store.
// =====================================================================
template <int EP, int GX, int GY, int GZ, int CHX, int CHY>
__global__ __launch_bounds__(256) void gemm_nt(const unsigned short* __restrict__ A,
                                               const unsigned short* __restrict__ B,
                                               int N, int LD, int Kext,
                                               unsigned short* __restrict__ Cbf,
                                               unsigned short* __restrict__ Cbf2) {
  constexpr int NRX = GX / CHX;
  constexpr int NRY = GY / CHY;
  static_assert(NRX * NRY * GZ == 8, "rect count must equal 8 XCDs");
  constexpr int GRP = 520;              // 8 rows * 64 + 8 pad (shorts)
  __shared__ __align__(16) unsigned short As[16 * GRP];
  __shared__ __align__(16) unsigned short Bs[16 * GRP];
  const int tid = threadIdx.x;
  const int w = tid >> 6, l = tid & 63;
  const int lm = l & 31, lh = l >> 5;   // frag m/n index, k-half
  const int wrow = (w >> 1) * 64, wcol = (w & 1) * 64;

  // XCD-locality remap: physical block l%8 -> XCD l%8 owns rect #(l%8)
  const int lb  = blockIdx.x;
  const int xcd = lb & 7, slot = lb >> 3;
  const int rx  = xcd % NRX, rem = xcd / NRX;
  const int ry  = rem % NRY, rz = rem / NRY;
  const int sx  = slot % CHX, sy = slot / CHX;
  const int bx  = rx * CHX + sx;
  const int by  = ry * CHY + sy;
  const int bz  = rz;

  const int m0 = by * 128, n0 = bx * 128;
  const int koff = bz * Kext;

  const int sr = l >> 3, sc = l & 7;
  const unsigned short* AgS = A + (size_t)(m0 + w * 32 + sr) * LD + koff + ((sc ^ sr) * 8);
  const unsigned short* BgS = B + (size_t)(n0 + w * 32 + sr) * LD + koff + ((sc ^ sr) * 8);
  unsigned short* AsW = &As[(w * 4) * GRP];   // wave w stages groups w*4..w*4+3
  unsigned short* BsW = &Bs[(w * 4) * GRP];

  f32x16 acc[2][2] = {};

  for (int k0 = 0; k0 < Kext; k0 += 64) {
    __syncthreads();
    #pragma unroll
    for (int off = 0; off < 32; off += 8) {
      GLL(AgS + k0 + (size_t)off * LD, AsW + (off >> 3) * GRP);
      GLL(BgS + k0 + (size_t)off * LD, BsW + (off >> 3) * GRP);
    }
    __syncthreads();
    sh8 af[2][4], bf2[2][4];
    #pragma unroll
    for (int i = 0; i < 2; i++) {
      const int r = wrow + i * 32 + lm;
      const int gb = (r >> 3) * GRP + (r & 7) * 64;
      #pragma unroll
      for (int s = 0; s < 4; s++)
        af[i][s] = *(const sh8*)&As[gb + (((2 * s + lh) ^ (r & 7)) * 8)];
    }
    #pragma unroll
    for (int j = 0; j < 2; j++) {
      const int r = wcol + j * 32 + lm;
      const int gb = (r >> 3) * GRP + (r & 7) * 64;
      #pragma unroll
      for (int s = 0; s < 4; s++)
        bf2[j][s] = *(const sh8*)&Bs[gb + (((2 * s + lh) ^ (r & 7)) * 8)];
    }
    #pragma unroll
    for (int s = 0; s < 4; s++)
      #pragma unroll
      for (int i = 0; i < 2; i++)
        #pragma unroll
        for (int j = 0; j < 2; j++)
          acc[i][j] = __builtin_amdgcn_mfma_f32_32x32x16_bf16(af[i][s], bf2[j][s], acc[i][j], 0, 0, 0);
  }

  unsigned short* C = bz ? Cbf2 : Cbf;
  #pragma unroll
  for (int i = 0; i < 2; i++) {
    #pragma unroll
    for (int j = 0; j < 2; j++) {
      #pragma unroll
      for (int reg = 0; reg < 16; reg++) {
        const int gm = m0 + wrow + i * 32 + (reg & 3) + 8 * (reg >> 2) + 4 * lh;
        const int gn = n0 + wcol + j * 32 + lm;
        float v = acc[i][j][reg];
        if (EP == 1) {
          // tanh-form GELU via exp2: g = v*e/(e+1), e = 2^(2.30219*(v+0.044715 v^3))
          const float vc = fminf(v, 8.0f);
          const float e = exp2f(2.3021906f * fmaf(0.044715f * vc * vc, vc, vc));
          v = v * e / (e + 1.0f);
        }
        C[(size_t)gm * N + gn] = f2b(v);
      }
    }
  }
}

// ---------------- Flash attention, causal, BM=64, BN=64, fixed-max softmax ----
__global__ __launch_bounds__(256) void attn_kernel(const unsigned short* __restrict__ qkv,
                                                   const unsigned short* __restrict__ vt,
                                                   unsigned short* __restrict__ p0,
                                                   unsigned short* __restrict__ p1,
                                                   float* __restrict__ l0,
                                                   float* __restrict__ l1) {
  const int bh = blockIdx.x;                    // XCD swizzle: bh fastest
  const int qt = (SEQ / 64 - 1) - blockIdx.y;   // reversed: long blocks first
  const int z  = blockIdx.z;
  const int b = bh >> 4, h = bh & 15;
  const int tid = threadIdx.x;
  const int w = tid >> 6, l = tid & 63, ln = tid & 15, quad = (tid & 63) >> 4;
  const int q0 = qt * 64;

  __shared__ __align__(16) unsigned short Ks[64 * 64];   // [key][d], chunk ^ (key&7)
  __shared__ __align__(16) unsigned short Vs[64 * 64];   // [d][key], chunk ^ (d&7)
  __shared__ __align__(16) unsigned short Ps[4][16 * 72];

  const size_t rstride = 3 * D_MODEL;
  const unsigned short* Qg = qkv + (size_t)b * SEQ * rstride + h * HD;
  const unsigned short* Kg = Qg + D_MODEL;
  const unsigned short* Vg = vt + ((size_t)b * D_MODEL + h * HD) * SEQ;

  sh8 qf[2];
  {
    const unsigned short* qrow = Qg + (size_t)(q0 + w * 16 + ln) * rstride + quad * 8;
    qf[0] = *(const sh8*)(qrow);
    qf[1] = *(const sh8*)(qrow + 32);
  }

  const int lr3 = l >> 3, lp3 = l & 7;
  const int cS = (lp3 ^ lr3) * 8;
  const unsigned short* KgS = Kg + (size_t)(w * 16 + lr3) * rstride + cS;
  unsigned short* KsW = &Ks[(w * 16) * 64];
  const unsigned short* VgS = Vg + (size_t)(w * 16 + lr3) * SEQ + cS;
  unsigned short* VsW = &Vs[(w * 16) * 64];
  unsigned short* Psw = &Ps[w][0];

  f32x4 o[4] = {};
  float lpart[4] = {0.f, 0.f, 0.f, 0.f};
  const int rbase = q0 + w * 16 + quad * 4;

  auto tile = [&](int kt, bool diag) {
    __syncthreads();
    GLL(KgS + (size_t)(kt * 64) * rstride,     KsW);
    GLL(KgS + (size_t)(kt * 64 + 8) * rstride, KsW + 8 * 64);
    GLL(VgS + kt * 64,           VsW);
    GLL(VgS + 8 * SEQ + kt * 64, VsW + 8 * 64);
    __syncthreads();

    #pragma unroll
    for (int ct = 0; ct < 4; ct++) {
      const int k = ct * 16 + ln;
      f32x4 zz = {};
      zz = __builtin_amdgcn_mfma_f32_16x16x32_bf16(
          qf[0], *(const sh8*)&Ks[k * 64 + ((quad ^ (k & 7)) * 8)], zz, 0, 0, 0);
      zz = __builtin_amdgcn_mfma_f32_16x16x32_bf16(
          qf[1], *(const sh8*)&Ks[k * 64 + (((4 + quad) ^ (k & 7)) * 8)], zz, 0, 0, 0);
      const int cg = kt * 64 + ct * 16 + ln;
      #pragma unroll
      for (int rr = 0; rr < 4; rr++) {
        float e = exp2f(fmaf(zz[rr], 0.18033688011112042f, -5.770780163555853f));
        if (diag && cg > rbase + rr) e = 0.0f;
        lpart[rr] += e;
        Psw[(quad * 4 + rr) * 72 + ct * 16 + ln] = f2b(e);
      }
    }

    #pragma unroll
    for (int kk = 0; kk < 2; kk++) {
      sh8 pf = *(const sh8*)&Psw[ln * 72 + kk * 32 + quad * 8];
      #pragma unroll
      for (int c2 = 0; c2 < 4; c2++) {
        const int d = c2 * 16 + ln;
        sh8 vf = *(const sh8*)&Vs[d * 64 + ((((kk * 4 + quad) ^ (d & 7))) * 8)];
        o[c2] = __builtin_amdgcn_mfma_f32_16x16x32_bf16(pf, vf, o[c2], 0, 0, 0);
      }
    }
  };

  // key-tiles of parity z (diagonal tile has parity qt&1)
  for (int kt = z; kt < qt; kt += 2) tile(kt, false);
  if ((qt & 1) == z) tile(qt, true);

  #pragma unroll
  for (int rr = 0; rr < 4; rr++) {
    #pragma unroll
    for (int off = 1; off < 16; off <<= 1) lpart[rr] += __shfl_xor(lpart[rr], off);
  }

  unsigned short* P = z ? p1 : p0;
  float* L = z ? l1 : l0;
  if (ln == 0) {
    #pragma unroll
    for (int rr = 0; rr < 4; rr++)
      L[((size_t)bh << 11) + q0 + w * 16 + quad * 4 + rr] = lpart[rr];
  }
  #pragma unroll
  for (int rr = 0; rr < 4; rr++) {
    const int row = q0 + w * 16 + quad * 4 + rr;
    const size_t base = ((size_t)b * SEQ + row) * D_MODEL + h * HD;
    #pragma unroll
    for (int c2 = 0; c2 < 4; c2++)
      P[base + c2 * 16 + ln] = f2b(o[c2][rr]);
  }
}

extern "C" void kernel_launch(void* const* d_in, const int* in_sizes, int n_in,
                              void* d_out, int out_size, void* d_ws, size_t ws_size,
                              hipStream_t stream) {
  const float* x    = (const float*)d_in[0];
  const float* Wq   = (const float*)d_in[1];
  const float* Wk   = (const float*)d_in[2];
  const float* Wv   = (const float*)d_in[3];
  const float* Wo   = (const float*)d_in[4];
  const float* Wup  = (const float*)d_in[5];
  const float* Wdn  = (const float*)d_in[6];
  const float* ln1m = (const float*)d_in[7];
  const float* ln1s = (const float*)d_in[8];
  const float* ln2m = (const float*)d_in[9];
  const float* ln2s = (const float*)d_in[10];
  float* out = (float*)d_out;

  unsigned short* ws = (unsigned short*)d_ws;
  size_t off = 0;
  unsigned short* wqkv = ws + off; off += (size_t)3072 * 1024;
  unsigned short* wo   = ws + off; off += (size_t)1024 * 1024;
  unsigned short* wup  = ws + off; off += (size_t)4096 * 1024;
  unsigned short* wdn  = ws + off; off += (size_t)1024 * 4096;
  unsigned short* xln  = ws + off; off += (size_t)NTOK * 1024;
  unsigned short* qkvb = ws + off; off += (size_t)NTOK * 3072;
  unsigned short* pre  = ws + off; off += (size_t)NTOK * 1024;
  unsigned short* mid  = qkvb;   // up-GEMM out [4096][4096] spans qkvb+pre exactly
  unsigned short* vtg  = xln;    // V^T aliases xln during attention (dead until LN2)
  unsigned short* po0  = qkvb;   // O-proj partials (qkvb dead after attn)
  unsigned short* po1  = qkvb + (size_t)NTOK * 1024;
  unsigned short* pd0  = ws;     // down partial 0: wqkv+wo region (weights dead)
  unsigned short* pd1  = xln;    // down partial 1 (NOT pre: pre aliases mid rows)
  // attention split-key scratch:
  unsigned short* ap1  = (unsigned short*)out;     // partial O (z=1); out dead until reduce_ln
  float* al0 = (float*)wqkv;                       // row-sums: wqkv region dead after QKV gemm
  float* al1 = al0 + (size_t)2 * NH * SEQ;

  // fused weight casts (12288 blocks x 1024 elems)
  cast6_kernel<<<12288, 256, 0, stream>>>(Wq, Wk, Wv, Wo, Wup, Wdn,
      wqkv, wqkv + (size_t)1024 * 1024, wqkv + (size_t)2 * 1024 * 1024, wo, wup, wdn);

  // LN1
  ln_kernel<<<NTOK, 256, 0, stream>>>(x, ln1m, ln1s, xln);
  // fused QKV projection: logical 24x32, XCD rect 12x8 (2x4 rects)
  gemm_nt<0, 24, 32, 1, 12, 8><<<768, 256, 0, stream>>>(xln, wqkv, 3072, 1024, 1024, qkvb, nullptr);
  // V transpose (xln region becomes vtg)
  vtrans_kernel<<<dim3(32, 32), 256, 0, stream>>>(qkvb, vtg);
  // causal flash attention, split-key z=2, XCD-swizzled grid (bh fastest)
  attn_kernel<<<dim3(2 * NH, SEQ / 64, 2), 256, 0, stream>>>(qkvb, vtg, pre, ap1, al0, al1);
  // combine: pre = (pre + ap1) / (al0 + al1)
  attn_combine_kernel<<<4096, 256, 0, stream>>>(pre, ap1, al0, al1);
  // O-projection: logical 8x32x2, XCD rect 4x16 (2x2x2 rects), split-K=2
  gemm_nt<0, 8, 32, 2, 4, 16><<<512, 256, 0, stream>>>(pre, wo, 1024, 1024, 512, po0, po1);
  // fused: out = x + po0 + po1 ; xln = LN2(out)
  reduce_ln_kernel<<<NTOK, 256, 0, stream>>>(po0, po1, x, ln2m, ln2s, out, xln);
  // MLP up + exp2-GELU: logical 32x32, XCD rect 8x16 (4x2 rects)
  gemm_nt<1, 32, 32, 1, 8, 16><<<1024, 256, 0, stream>>>(xln, wup, 4096, 1024, 1024, mid, nullptr);
  // MLP down: logical 8x32x2, XCD rect 8x8 (1x4x2 rects), split-K=2
  gemm_nt<0, 8, 32, 2, 8, 8><<<512, 256, 0, stream>>>(mid, wdn, 1024, 4096, 2048, pd0, pd1);
  // out += pd0 + pd1
  reduce2_kernel<<<4096, 256, 0, stream>>>(pd0, pd1, out);
}

// Round 11
// 327.293 us; speedup vs baseline: 1.0876x; 1.0110x over previous
//
#include <hip/hip_runtime.h>
#include <hip/hip_bf16.h>
#include <cstdint>
#include <cstddef>

#define D_MODEL 1024
#define SEQ     2048
#define NTOK    4096   // B*S
#define NH      16
#define HD      64

typedef __attribute__((ext_vector_type(8))) short sh8;
typedef __attribute__((ext_vector_type(4))) float f32x4;
typedef __attribute__((ext_vector_type(16))) float f32x16;

#define GLL(g, s) __builtin_amdgcn_global_load_lds(                                   \
    (const __attribute__((address_space(1))) void*)(g),                               \
    (__attribute__((address_space(3))) void*)(s), 16, 0, 0)

__device__ __forceinline__ unsigned short f2b(float f) {
  union { float f; unsigned u; } v; v.f = f;
  unsigned r = v.u + 0x7FFFu + ((v.u >> 16) & 1u);
  return (unsigned short)(r >> 16);
}
__device__ __forceinline__ float b2f(unsigned short h) {
  union { unsigned u; float f; } v; v.u = ((unsigned)h) << 16;
  return v.f;
}

// ---------------- fused fp32 -> bf16 cast for all 6 weights ----------------
__global__ __launch_bounds__(256) void cast6_kernel(
    const float* __restrict__ q, const float* __restrict__ k, const float* __restrict__ v,
    const float* __restrict__ o, const float* __restrict__ u, const float* __restrict__ d,
    unsigned short* __restrict__ oq, unsigned short* __restrict__ ok,
    unsigned short* __restrict__ ov, unsigned short* __restrict__ oo,
    unsigned short* __restrict__ ou, unsigned short* __restrict__ od) {
  int bid = blockIdx.x;
  const float* src; unsigned short* dst; int base;
  if      (bid < 1024) { src = q; dst = oq; base = bid; }
  else if (bid < 2048) { src = k; dst = ok; base = bid - 1024; }
  else if (bid < 3072) { src = v; dst = ov; base = bid - 2048; }
  else if (bid < 4096) { src = o; dst = oo; base = bid - 3072; }
  else if (bid < 8192) { src = u; dst = ou; base = bid - 4096; }
  else                 { src = d; dst = od; base = bid - 8192; }
  int i = base * 1024 + threadIdx.x * 4;
  float4 vv = *(const float4*)(src + i);
  ushort4 w;
  w.x = f2b(vv.x); w.y = f2b(vv.y); w.z = f2b(vv.z); w.w = f2b(vv.w);
  *(ushort4*)(dst + i) = w;
}

// ---------------- LayerNorm (torch var ddof=1), bf16 out ----------------
__global__ __launch_bounds__(256) void ln_kernel(const float* __restrict__ x,
                                                 const float* __restrict__ msc,
                                                 const float* __restrict__ ssc,
                                                 unsigned short* __restrict__ out) {
  const int t = blockIdx.x;
  const int tid = threadIdx.x;
  const float4 v = ((const float4*)(x + (size_t)t * D_MODEL))[tid];
  float s = v.x + v.y + v.z + v.w;
  float q = v.x * v.x + v.y * v.y + v.z * v.z + v.w * v.w;
  #pragma unroll
  for (int off = 32; off; off >>= 1) {
    s += __shfl_xor(s, off);
    q += __shfl_xor(q, off);
  }
  __shared__ float sh[8];
  const int w = tid >> 6;
  if ((tid & 63) == 0) { sh[w * 2] = s; sh[w * 2 + 1] = q; }
  __syncthreads();
  s = sh[0] + sh[2] + sh[4] + sh[6];
  q = sh[1] + sh[3] + sh[5] + sh[7];
  const float mean = s * (1.0f / D_MODEL);
  const float var = (q - (float)D_MODEL * mean * mean) * (1.0f / (D_MODEL - 1));
  const float rstd = rsqrtf(var + 1e-9f);
  const float4 ms = ((const float4*)msc)[tid];
  const float4 ss = ((const float4*)ssc)[tid];
  ushort4 o;
  o.x = f2b((v.x - mean) * rstd * ss.x + ms.x);
  o.y = f2b((v.y - mean) * rstd * ss.y + ms.y);
  o.z = f2b((v.z - mean) * rstd * ss.z + ms.z);
  o.w = f2b((v.w - mean) * rstd * ss.w + ms.w);
  ((ushort4*)(out + (size_t)t * D_MODEL))[tid] = o;
}

// -------- fused: out = x + p0 + p1 ; oln = LN2(out) (one pass per row) --------
__global__ __launch_bounds__(256) void reduce_ln_kernel(
    const unsigned short* __restrict__ p0, const unsigned short* __restrict__ p1,
    const float* __restrict__ x, const float* __restrict__ msc,
    const float* __restrict__ ssc, float* __restrict__ out,
    unsigned short* __restrict__ oln) {
  const int t = blockIdx.x;
  const int tid = threadIdx.x;
  const size_t base = (size_t)t * D_MODEL + tid * 4;
  ushort4 a = *(const ushort4*)(p0 + base);
  ushort4 b = *(const ushort4*)(p1 + base);
  float4 xv = *(const float4*)(x + base);
  float4 r;
  r.x = xv.x + b2f(a.x) + b2f(b.x);
  r.y = xv.y + b2f(a.y) + b2f(b.y);
  r.z = xv.z + b2f(a.z) + b2f(b.z);
  r.w = xv.w + b2f(a.w) + b2f(b.w);
  *(float4*)(out + base) = r;
  float s = r.x + r.y + r.z + r.w;
  float q = r.x * r.x + r.y * r.y + r.z * r.z + r.w * r.w;
  #pragma unroll
  for (int off = 32; off; off >>= 1) {
    s += __shfl_xor(s, off);
    q += __shfl_xor(q, off);
  }
  __shared__ float sh[8];
  const int w = tid >> 6;
  if ((tid & 63) == 0) { sh[w * 2] = s; sh[w * 2 + 1] = q; }
  __syncthreads();
  s = sh[0] + sh[2] + sh[4] + sh[6];
  q = sh[1] + sh[3] + sh[5] + sh[7];
  const float mean = s * (1.0f / D_MODEL);
  const float var = (q - (float)D_MODEL * mean * mean) * (1.0f / (D_MODEL - 1));
  const float rstd = rsqrtf(var + 1e-9f);
  const float4 ms = ((const float4*)msc)[tid];
  const float4 ss = ((const float4*)ssc)[tid];
  ushort4 o;
  o.x = f2b((r.x - mean) * rstd * ss.x + ms.x);
  o.y = f2b((r.y - mean) * rstd * ss.y + ms.y);
  o.z = f2b((r.z - mean) * rstd * ss.z + ms.z);
  o.w = f2b((r.w - mean) * rstd * ss.w + ms.w);
  *(ushort4*)(oln + base) = o;
}

// ---------------- split-K partial reduce: out += p0 + p1 ----------------------
__global__ __launch_bounds__(256) void reduce2_kernel(const unsigned short* __restrict__ p0,
                                                      const unsigned short* __restrict__ p1,
                                                      float* __restrict__ out) {
  int i = (blockIdx.x * 256 + threadIdx.x) * 4;
  ushort4 a = *(const ushort4*)(p0 + i);
  ushort4 b = *(const ushort4*)(p1 + i);
  float4 base = *(const float4*)(out + i);
  float4 r;
  r.x = base.x + b2f(a.x) + b2f(b.x);
  r.y = base.y + b2f(a.y) + b2f(b.y);
  r.z = base.z + b2f(a.z) + b2f(b.z);
  r.w = base.w + b2f(a.w) + b2f(b.w);
  *(float4*)(out + i) = r;
}

// ---------------- attention split-key combine: pre = (p0+p1)/(l0+l1) ----------
__global__ __launch_bounds__(256) void attn_combine_kernel(
    unsigned short* __restrict__ p0, const unsigned short* __restrict__ p1,
    const float* __restrict__ l0, const float* __restrict__ l1) {
  int i = (blockIdx.x * 256 + threadIdx.x) * 4;
  const int tok = i >> 10, ch = i & 1023;
  const int b = tok >> 11, s = tok & 2047, h = ch >> 6;
  const int lidx = ((b << 4) + h) * 2048 + s;
  const float inv = 1.0f / (l0[lidx] + l1[lidx]);
  ushort4 a = *(const ushort4*)(p0 + i);
  ushort4 c = *(const ushort4*)(p1 + i);
  ushort4 r;
  r.x = f2b((b2f(a.x) + b2f(c.x)) * inv);
  r.y = f2b((b2f(a.y) + b2f(c.y)) * inv);
  r.z = f2b((b2f(a.z) + b2f(c.z)) * inv);
  r.w = f2b((b2f(a.w) + b2f(c.w)) * inv);
  *(ushort4*)(p0 + i) = r;
}

// ---------------- V transpose: qkv[tok][2048+d] -> vt[b][d][s] ----------------
__global__ __launch_bounds__(256) void vtrans_kernel(const unsigned short* __restrict__ qkv,
                                                     unsigned short* __restrict__ vt) {
  __shared__ unsigned short T[64][72];
  const int st = blockIdx.x;            // s-tile 0..31
  const int b  = blockIdx.y >> 4;
  const int dt = blockIdx.y & 15;       // d-tile 0..15
  const int tid = threadIdx.x;
  const int s0 = st * 64, d0 = dt * 64;
  const int r = tid >> 2, c0 = (tid & 3) * 16;
  const unsigned short* src = qkv + ((size_t)b * SEQ + s0 + r) * 3072 + 2 * D_MODEL + d0 + c0;
  *(uint4*)&T[r][c0]     = *(const uint4*)(src);
  *(uint4*)&T[r][c0 + 8] = *(const uint4*)(src + 8);
  __syncthreads();
  unsigned short buf[16] __attribute__((aligned(16)));
  #pragma unroll
  for (int j = 0; j < 16; j++) buf[j] = T[c0 + j][r];
  unsigned short* dst = vt + ((size_t)b * D_MODEL + d0 + r) * SEQ + s0 + c0;
  *(uint4*)(dst)     = *(uint4*)&buf[0];
  *(uint4*)(dst + 8) = *(uint4*)&buf[8];
}

// =====================================================================
// 128x128 NT GEMM — R11: 32x32x16 MFMA with UNIFORM [128][64] LDS layout
// (all GLL dests 1024B-aligned, as R5) and 32-row XOR swizzle:
//   swz(r) = (r&7) ^ ((r>>3)&3)
// Write: GLL group g stages rows 8g..8g+7; lane (sr,sc) sources global
// chunk (sc ^ sr ^ (g&3)) -> LDS[row][phys p] holds logical chunk
// p ^ swz(row).  Read: phys chunk = s' ^ (lm&7) ^ (lm>>3).  Rows
// {q,q+8,q+16,q+24} now map to 4 DISTINCT bank-quads for any logical
// chunk, with zero padding (R10's 1040B group stride put GLL bursts at
// 16-mod-128 bases -> 4.2M bank-conflict cycles; this restores aligned
// bursts).  C/D mapping (HW-verified m74): col=l&31,
// row=(reg&3)+8*(reg>>2)+4*(l>>5).
// EP: 0 = bf16 store, 1 = exp2-GELU bf16 store.
// =====================================================================
template <int EP, int GX, int GY, int GZ, int CHX, int CHY>
__global__ __launch_bounds__(256) void gemm_nt(const unsigned short* __restrict__ A,
                                               const unsigned short* __restrict__ B,
                                               int N, int LD, int Kext,
                                               unsigned short* __restrict__ Cbf,
                                               unsigned short* __restrict__ Cbf2) {
  constexpr int NRX = GX / CHX;
  constexpr int NRY = GY / CHY;
  static_assert(NRX * NRY * GZ == 8, "rect count must equal 8 XCDs");
  __shared__ __align__(16) unsigned short As[128 * 64];
  __shared__ __align__(16) unsigned short Bs[128 * 64];
  const int tid = threadIdx.x;
  const int w = tid >> 6, l = tid & 63;
  const int lm = l & 31, lh = l >> 5;   // frag m/n index, k-half
  const int wrow = (w >> 1) * 64, wcol = (w & 1) * 64;

  // XCD-locality remap: physical block l%8 -> XCD l%8 owns rect #(l%8)
  const int lb  = blockIdx.x;
  const int xcd = lb & 7, slot = lb >> 3;
  const int rx  = xcd % NRX, rem = xcd / NRX;
  const int ry  = rem % NRY, rz = rem / NRY;
  const int sx  = slot % CHX, sy = slot / CHX;
  const int bx  = rx * CHX + sx;
  const int by  = ry * CHY + sy;
  const int bz  = rz;

  const int m0 = by * 128, n0 = bx * 128;
  const int koff = bz * Kext;

  const int sr = l >> 3, sc = l & 7;
  // row pointers WITHOUT chunk offset; per-GLL chunk = (sc^sr^g)*8
  const unsigned short* AgR = A + (size_t)(m0 + w * 32 + sr) * LD + koff;
  const unsigned short* BgR = B + (size_t)(n0 + w * 32 + sr) * LD + koff;
  unsigned short* AsW = &As[(w * 32) * 64];
  unsigned short* BsW = &Bs[(w * 32) * 64];

  f32x16 acc[2][2] = {};
  const int sz = (lm & 7) ^ (lm >> 3);  // swz(r) for this lane's frag rows

  for (int k0 = 0; k0 < Kext; k0 += 64) {
    __syncthreads();
    #pragma unroll
    for (int off = 0; off < 32; off += 8) {
      const int g = off >> 3;
      const int co = ((sc ^ sr ^ g) * 8);
      GLL(AgR + k0 + (size_t)off * LD + co, AsW + off * 64);
      GLL(BgR + k0 + (size_t)off * LD + co, BsW + off * 64);
    }
    __syncthreads();
    sh8 af[2][4], bf2[2][4];
    #pragma unroll
    for (int i = 0; i < 2; i++) {
      const int r = wrow + i * 32 + lm;
      #pragma unroll
      for (int s = 0; s < 4; s++)
        af[i][s] = *(const sh8*)&As[r * 64 + (((2 * s + lh) ^ sz) * 8)];
    }
    #pragma unroll
    for (int j = 0; j < 2; j++) {
      const int r = wcol + j * 32 + lm;
      #pragma unroll
      for (int s = 0; s < 4; s++)
        bf2[j][s] = *(const sh8*)&Bs[r * 64 + (((2 * s + lh) ^ sz) * 8)];
    }
    #pragma unroll
    for (int s = 0; s < 4; s++)
      #pragma unroll
      for (int i = 0; i < 2; i++)
        #pragma unroll
        for (int j = 0; j < 2; j++)
          acc[i][j] = __builtin_amdgcn_mfma_f32_32x32x16_bf16(af[i][s], bf2[j][s], acc[i][j], 0, 0, 0);
  }

  unsigned short* C = bz ? Cbf2 : Cbf;
  #pragma unroll
  for (int i = 0; i < 2; i++) {
    #pragma unroll
    for (int j = 0; j < 2; j++) {
      #pragma unroll
      for (int reg = 0; reg < 16; reg++) {
        const int gm = m0 + wrow + i * 32 + (reg & 3) + 8 * (reg >> 2) + 4 * lh;
        const int gn = n0 + wcol + j * 32 + lm;
        float v = acc[i][j][reg];
        if (EP == 1) {
          // tanh-form GELU via exp2: g = v*e/(e+1), e = 2^(2.30219*(v+0.044715 v^3))
          const float vc = fminf(v, 8.0f);
          const float e = exp2f(2.3021906f * fmaf(0.044715f * vc * vc, vc, vc));
          v = v * e / (e + 1.0f);
        }
        C[(size_t)gm * N + gn] = f2b(v);
      }
    }
  }
}

// ---------------- Flash attention, causal, BM=64, BN=64, fixed-max softmax ----
__global__ __launch_bounds__(256) void attn_kernel(const unsigned short* __restrict__ qkv,
                                                   const unsigned short* __restrict__ vt,
                                                   unsigned short* __restrict__ p0,
                                                   unsigned short* __restrict__ p1,
                                                   float* __restrict__ l0,
                                                   float* __restrict__ l1) {
  const int bh = blockIdx.x;                    // XCD swizzle: bh fastest
  const int qt = (SEQ / 64 - 1) - blockIdx.y;   // reversed: long blocks first
  const int z  = blockIdx.z;
  const int b = bh >> 4, h = bh & 15;
  const int tid = threadIdx.x;
  const int w = tid >> 6, l = tid & 63, ln = tid & 15, quad = (tid & 63) >> 4;
  const int q0 = qt * 64;

  __shared__ __align__(16) unsigned short Ks[64 * 64];   // [key][d], chunk ^ (key&7)
  __shared__ __align__(16) unsigned short Vs[64 * 64];   // [d][key], chunk ^ (d&7)
  __shared__ __align__(16) unsigned short Ps[4][16 * 72];

  const size_t rstride = 3 * D_MODEL;
  const unsigned short* Qg = qkv + (size_t)b * SEQ * rstride + h * HD;
  const unsigned short* Kg = Qg + D_MODEL;
  const unsigned short* Vg = vt + ((size_t)b * D_MODEL + h * HD) * SEQ;

  sh8 qf[2];
  {
    const unsigned short* qrow = Qg + (size_t)(q0 + w * 16 + ln) * rstride + quad * 8;
    qf[0] = *(const sh8*)(qrow);
    qf[1] = *(const sh8*)(qrow + 32);
  }

  const int lr3 = l >> 3, lp3 = l & 7;
  const int cS = (lp3 ^ lr3) * 8;
  const unsigned short* KgS = Kg + (size_t)(w * 16 + lr3) * rstride + cS;
  unsigned short* KsW = &Ks[(w * 16) * 64];
  const unsigned short* VgS = Vg + (size_t)(w * 16 + lr3) * SEQ + cS;
  unsigned short* VsW = &Vs[(w * 16) * 64];
  unsigned short* Psw = &Ps[w][0];

  f32x4 o[4] = {};
  float lpart[4] = {0.f, 0.f, 0.f, 0.f};
  const int rbase = q0 + w * 16 + quad * 4;

  auto tile = [&](int kt, bool diag) {
    __syncthreads();
    GLL(KgS + (size_t)(kt * 64) * rstride,     KsW);
    GLL(KgS + (size_t)(kt * 64 + 8) * rstride, KsW + 8 * 64);
    GLL(VgS + kt * 64,           VsW);
    GLL(VgS + 8 * SEQ + kt * 64, VsW + 8 * 64);
    __syncthreads();

    #pragma unroll
    for (int ct = 0; ct < 4; ct++) {
      const int k = ct * 16 + ln;
      f32x4 zz = {};
      zz = __builtin_amdgcn_mfma_f32_16x16x32_bf16(
          qf[0], *(const sh8*)&Ks[k * 64 + ((quad ^ (k & 7)) * 8)], zz, 0, 0, 0);
      zz = __builtin_amdgcn_mfma_f32_16x16x32_bf16(
          qf[1], *(const sh8*)&Ks[k * 64 + (((4 + quad) ^ (k & 7)) * 8)], zz, 0, 0, 0);
      const int cg = kt * 64 + ct * 16 + ln;
      #pragma unroll
      for (int rr = 0; rr < 4; rr++) {
        float e = exp2f(fmaf(zz[rr], 0.18033688011112042f, -5.770780163555853f));
        if (diag && cg > rbase + rr) e = 0.0f;
        lpart[rr] += e;
        Psw[(quad * 4 + rr) * 72 + ct * 16 + ln] = f2b(e);
      }
    }

    #pragma unroll
    for (int kk = 0; kk < 2; kk++) {
      sh8 pf = *(const sh8*)&Psw[ln * 72 + kk * 32 + quad * 8];
      #pragma unroll
      for (int c2 = 0; c2 < 4; c2++) {
        const int d = c2 * 16 + ln;
        sh8 vf = *(const sh8*)&Vs[d * 64 + ((((kk * 4 + quad) ^ (d & 7))) * 8)];
        o[c2] = __builtin_amdgcn_mfma_f32_16x16x32_bf16(pf, vf, o[c2], 0, 0, 0);
      }
    }
  };

  // key-tiles of parity z (diagonal tile has parity qt&1)
  for (int kt = z; kt < qt; kt += 2) tile(kt, false);
  if ((qt & 1) == z) tile(qt, true);

  #pragma unroll
  for (int rr = 0; rr < 4; rr++) {
    #pragma unroll
    for (int off = 1; off < 16; off <<= 1) lpart[rr] += __shfl_xor(lpart[rr], off);
  }

  unsigned short* P = z ? p1 : p0;
  float* L = z ? l1 : l0;
  if (ln == 0) {
    #pragma unroll
    for (int rr = 0; rr < 4; rr++)
      L[((size_t)bh << 11) + q0 + w * 16 + quad * 4 + rr] = lpart[rr];
  }
  #pragma unroll
  for (int rr = 0; rr < 4; rr++) {
    const int row = q0 + w * 16 + quad * 4 + rr;
    const size_t base = ((size_t)b * SEQ + row) * D_MODEL + h * HD;
    #pragma unroll
    for (int c2 = 0; c2 < 4; c2++)
      P[base + c2 * 16 + ln] = f2b(o[c2][rr]);
  }
}

extern "C" void kernel_launch(void* const* d_in, const int* in_sizes, int n_in,
                              void* d_out, int out_size, void* d_ws, size_t ws_size,
                              hipStream_t stream) {
  const float* x    = (const float*)d_in[0];
  const float* Wq   = (const float*)d_in[1];
  const float* Wk   = (const float*)d_in[2];
  const float* Wv   = (const float*)d_in[3];
  const float* Wo   = (const float*)d_in[4];
  const float* Wup  = (const float*)d_in[5];
  const float* Wdn  = (const float*)d_in[6];
  const float* ln1m = (const float*)d_in[7];
  const float* ln1s = (const float*)d_in[8];
  const float* ln2m = (const float*)d_in[9];
  const float* ln2s = (const float*)d_in[10];
  float* out = (float*)d_out;

  unsigned short* ws = (unsigned short*)d_ws;
  size_t off = 0;
  unsigned short* wqkv = ws + off; off += (size_t)3072 * 1024;
  unsigned short* wo   = ws + off; off += (size_t)1024 * 1024;
  unsigned short* wup  = ws + off; off += (size_t)4096 * 1024;
  unsigned short* wdn  = ws + off; off += (size_t)1024 * 4096;
  unsigned short* xln  = ws + off; off += (size_t)NTOK * 1024;
  unsigned short* qkvb = ws + off; off += (size_t)NTOK * 3072;
  unsigned short* pre  = ws + off; off += (size_t)NTOK * 1024;
  unsigned short* mid  = qkvb;   // up-GEMM out [4096][4096] spans qkvb+pre exactly
  unsigned short* vtg  = xln;    // V^T aliases xln during attention (dead until LN2)
  unsigned short* po0  = qkvb;   // O-proj partials (qkvb dead after attn)
  unsigned short* po1  = qkvb + (size_t)NTOK * 1024;
  unsigned short* pd0  = ws;     // down partial 0: wqkv+wo region (weights dead)
  unsigned short* pd1  = xln;    // down partial 1 (NOT pre: pre aliases mid rows)
  // attention split-key scratch:
  unsigned short* ap1  = (unsigned short*)out;     // partial O (z=1); out dead until reduce_ln
  float* al0 = (float*)wqkv;                       // row-sums: wqkv region dead after QKV gemm
  float* al1 = al0 + (size_t)2 * NH * SEQ;

  // fused weight casts (12288 blocks x 1024 elems)
  cast6_kernel<<<12288, 256, 0, stream>>>(Wq, Wk, Wv, Wo, Wup, Wdn,
      wqkv, wqkv + (size_t)1024 * 1024, wqkv + (size_t)2 * 1024 * 1024, wo, wup, wdn);

  // LN1
  ln_kernel<<<NTOK, 256, 0, stream>>>(x, ln1m, ln1s, xln);
  // fused QKV projection: logical 24x32, XCD rect 12x8 (2x4 rects)
  gemm_nt<0, 24, 32, 1, 12, 8><<<768, 256, 0, stream>>>(xln, wqkv, 3072, 1024, 1024, qkvb, nullptr);
  // V transpose (xln region becomes vtg)
  vtrans_kernel<<<dim3(32, 32), 256, 0, stream>>>(qkvb, vtg);
  // causal flash attention, split-key z=2, XCD-swizzled grid (bh fastest)
  attn_kernel<<<dim3(2 * NH, SEQ / 64, 2), 256, 0, stream>>>(qkvb, vtg, pre, ap1, al0, al1);
  // combine: pre = (pre + ap1) / (al0 + al1)
  attn_combine_kernel<<<4096, 256, 0, stream>>>(pre, ap1, al0, al1);
  // O-projection: logical 8x32x2, XCD rect 4x16 (2x2x2 rects), split-K=2
  gemm_nt<0, 8, 32, 2, 4, 16><<<512, 256, 0, stream>>>(pre, wo, 1024, 1024, 512, po0, po1);
  // fused: out = x + po0 + po1 ; xln = LN2(out)
  reduce_ln_kernel<<<NTOK, 256, 0, stream>>>(po0, po1, x, ln2m, ln2s, out, xln);
  // MLP up + exp2-GELU: logical 32x32, XCD rect 8x16 (4x2 rects)
  gemm_nt<1, 32, 32, 1, 8, 16><<<1024, 256, 0, stream>>>(xln, wup, 4096, 1024, 1024, mid, nullptr);
  // MLP down: logical 8x32x2, XCD rect 8x8 (1x4x2 rects), split-K=2
  gemm_nt<0, 8, 32, 2, 8, 8><<<512, 256, 0, stream>>>(mid, wdn, 1024, 4096, 2048, pd0, pd1);
  // out += pd0 + pd1
  reduce2_kernel<<<4096, 256, 0, stream>>>(pd0, pd1, out);
}